// Round 10
// baseline (433.595 us; speedup 1.0000x reference)
//
#include <hip/hip_runtime.h>
#include <math.h>

#define BB 4
#define LL 2048
#define DM 1024
#define DI 2048
#define DS 16
#define DTR 64
#define TCH 256          // channels per scan block
#define TT 16            // timesteps per BC tile

typedef unsigned short bf16;
typedef __attribute__((ext_vector_type(8))) short bf16x8;
typedef __attribute__((ext_vector_type(4))) float f32x4;

__device__ inline float b2f(bf16 u) { return __uint_as_float(((unsigned)u) << 16); }
__device__ inline bf16 f2b(float f) {
    unsigned u = __float_as_uint(f);
    u += 0x7FFF + ((u >> 16) & 1);   // round-to-nearest-even
    return (bf16)(u >> 16);
}

__device__ inline float4 ld4(const float* p) { return *(const float4*)p; }
__device__ inline float4 ld4(const bf16* p) {
    ushort4 v = *(const ushort4*)p;
    return make_float4(b2f(v.x), b2f(v.y), b2f(v.z), b2f(v.w));
}
__device__ inline void st1(float* p, float v) { *p = v; }
__device__ inline void st1(bf16* p, float v) { *p = f2b(v); }

// cheap softplus: hw v_exp_f32/v_log_f32 (~8 VALU instrs); bf16-sufficient.
__device__ inline float softplus_fast(float v) {
    return (v > 15.f) ? v : __logf(1.f + __expf(v));
}

// async global->LDS, 16 bytes per lane; LDS dest = wave-uniform base + lane*16
__device__ inline void gld_lds16(const void* g, void* l) {
    __builtin_amdgcn_global_load_lds(
        (const __attribute__((address_space(1))) unsigned int*)g,
        (__attribute__((address_space(3))) unsigned int*)l, 16, 0, 0);
}

// dA[s] = c1^(s+1) via addition-chain tree: 15 muls, dep depth 4 (vs 15).
__device__ inline void dA_tree(float c1, float* dA) {
    float c2 = c1 * c1;
    float c4 = c2 * c2;
    float c8 = c4 * c4;
    dA[0]  = c1;        dA[1]  = c2;        dA[2]  = c2 * c1;
    dA[3]  = c4;        dA[4]  = c4 * c1;   dA[5]  = c4 * c2;
    dA[6]  = c4 * dA[2];dA[7]  = c8;        dA[8]  = c8 * c1;
    dA[9]  = c8 * c2;   dA[10] = c8 * dA[2];dA[11] = c8 * c4;
    dA[12] = c8 * dA[4];dA[13] = c8 * dA[5];dA[14] = c8 * dA[6];
    dA[15] = c8 * c8;
}

// ---------------- f32 -> bf16 convert (late W_out fallback only) -------------
__global__ __launch_bounds__(256) void f2b_kernel(const float* __restrict__ in,
    bf16* __restrict__ out, int n4)
{
    int i = blockIdx.x * 256 + threadIdx.x;
    if (i >= n4) return;
    float4 v = *(const float4*)(in + (size_t)i * 4);
    ushort4 o = { f2b(v.x), f2b(v.y), f2b(v.z), f2b(v.w) };
    *(ushort4*)(out + (size_t)i * 4) = o;
}

// ---------------- Fused prologue: LayerNorm + all weight converts ------------
__global__ __launch_bounds__(256) void prep_kernel(
    const float* __restrict__ x, const float* __restrict__ lw,
    const float* __restrict__ lb, bf16* __restrict__ xn,
    const float* __restrict__ W_in, bf16* __restrict__ W_in_b,
    const float* __restrict__ W_x, bf16* __restrict__ W_x_b,
    const float* __restrict__ W_dt, bf16* __restrict__ W_dt_b,
    const float* __restrict__ cw, bf16* __restrict__ cwt,
    const float* __restrict__ W_out, bf16* __restrict__ W_out_b,
    int dofast, int dowout)
{
    int blk = blockIdx.x;
    int tid = threadIdx.x;
    if (blk < BB * LL) {                       // ---- LayerNorm row ----
        int row = blk;
        const float* xr = x + (size_t)row * DM;
        float4 v = *(const float4*)(xr + tid * 4);
        float s1 = v.x + v.y + v.z + v.w;
        float s2 = v.x * v.x + v.y * v.y + v.z * v.z + v.w * v.w;
        #pragma unroll
        for (int o = 32; o > 0; o >>= 1) {
            s1 += __shfl_xor(s1, o);
            s2 += __shfl_xor(s2, o);
        }
        __shared__ float r1[4], r2[4];
        __shared__ float smu, srs;
        int wv = tid >> 6;
        if ((tid & 63) == 0) { r1[wv] = s1; r2[wv] = s2; }
        __syncthreads();
        if (tid == 0) {
            float t1 = r1[0] + r1[1] + r1[2] + r1[3];
            float t2 = r2[0] + r2[1] + r2[2] + r2[3];
            float mu = t1 * (1.0f / DM);
            float var = t2 * (1.0f / DM) - mu * mu;
            smu = mu;
            srs = rsqrtf(var + 1e-5f);
        }
        __syncthreads();
        float mu = smu, rs = srs;
        float4 wv4 = *(const float4*)(lw + tid * 4);
        float4 bv4 = *(const float4*)(lb + tid * 4);
        ushort4 o;
        o.x = f2b((v.x - mu) * rs * wv4.x + bv4.x);
        o.y = f2b((v.y - mu) * rs * wv4.y + bv4.y);
        o.z = f2b((v.z - mu) * rs * wv4.z + bv4.z);
        o.w = f2b((v.w - mu) * rs * wv4.w + bv4.w);
        *(ushort4*)(xn + (size_t)row * DM + tid * 4) = o;
        return;
    }
    blk -= BB * LL;
    if (blk < 4096) {                          // ---- W_in f2b ----
        int i = blk * 256 + tid;
        float4 v = *(const float4*)(W_in + (size_t)i * 4);
        ushort4 o = { f2b(v.x), f2b(v.y), f2b(v.z), f2b(v.w) };
        *(ushort4*)(W_in_b + (size_t)i * 4) = o;
        return;
    }
    blk -= 4096;
    if (!dofast) return;
    if (blk < 192) {                           // ---- W_x f2b ----
        int i = blk * 256 + tid;
        float4 v = *(const float4*)(W_x + (size_t)i * 4);
        ushort4 o = { f2b(v.x), f2b(v.y), f2b(v.z), f2b(v.w) };
        *(ushort4*)(W_x_b + (size_t)i * 4) = o;
        return;
    }
    blk -= 192;
    if (blk < 128) {                           // ---- W_dt f2b ----
        int i = blk * 256 + tid;
        float4 v = *(const float4*)(W_dt + (size_t)i * 4);
        ushort4 o = { f2b(v.x), f2b(v.y), f2b(v.z), f2b(v.w) };
        *(ushort4*)(W_dt_b + (size_t)i * 4) = o;
        return;
    }
    blk -= 128;
    if (blk < 8) {                             // ---- conv weight transpose ----
        int d = blk * 256 + tid;
        float4 w = *(const float4*)(cw + d * 4);
        cwt[0 * DI + d] = f2b(w.x);
        cwt[1 * DI + d] = f2b(w.y);
        cwt[2 * DI + d] = f2b(w.z);
        cwt[3 * DI + d] = f2b(w.w);
        return;
    }
    blk -= 8;
    if (dowout && blk < 2048) {                // ---- W_out f2b ----
        int i = blk * 256 + tid;
        float4 v = *(const float4*)(W_out + (size_t)i * 4);
        ushort4 o = { f2b(v.x), f2b(v.y), f2b(v.z), f2b(v.w) };
        *(ushort4*)(W_out_b + (size_t)i * 4) = o;
    }
}

// ============================================================================
// 256x256 8-phase MFMA GEMM (NT), WAR-interleaved fragment prefetch.
// ============================================================================
#define BARR  do { asm volatile("" ::: "memory"); __builtin_amdgcn_s_barrier(); \
                   asm volatile("" ::: "memory"); } while (0)
#define LGKM0 do { asm volatile("s_waitcnt lgkmcnt(0)" ::: "memory"); \
                   __builtin_amdgcn_sched_barrier(0); } while (0)
#define VMC4  asm volatile("s_waitcnt vmcnt(4)" ::: "memory")
#define VMC2  asm volatile("s_waitcnt vmcnt(2)" ::: "memory")
#define SCHED0 __builtin_amdgcn_sched_barrier(0)

template<int EPI, typename TC>
__global__ __launch_bounds__(512, 2) void gemm_8p(
    const bf16* __restrict__ A, int lda,
    const bf16* __restrict__ B, int ldb,
    TC* __restrict__ C, int ldc,
    int K, const float* __restrict__ aux, int nbn)
{
    __shared__ bf16 lds[65536];          // 128 KB: A [0,64K) B [64K,128K)
    char* L = (char*)lds;
    const int tid = threadIdx.x;
    const int lane = tid & 63;
    const int w = tid >> 6;              // 0..7
    const int wm = w >> 2;               // 0..1
    const int wn = w & 3;                // 0..3

    int nwg = gridDim.x;
    int bid = blockIdx.x;
    int sb = bid;
    if ((nwg & 7) == 0) sb = (bid & 7) * (nwg >> 3) + (bid >> 3);
    const int m0 = (sb / nbn) * 256;
    const int n0 = (sb % nbn) * 256;

    const size_t lda2 = (size_t)lda * 2;
    const size_t ldb2 = (size_t)ldb * 2;
    const int l8 = lane >> 3;
    const int scol = ((lane & 7) ^ l8) << 4;
    const size_t offA = (size_t)(w * 8 + l8) * lda2 + scol;
    const size_t offB = (size_t)(w * 8 + l8) * ldb2 + scol;
    const char* Ab = (const char*)A + (size_t)m0 * lda2;
    const char* Bb = (const char*)B + (size_t)n0 * ldb2;

    const int fm = lane & 15, fq = lane >> 4;
    const int prow = fm * 128;
    const int px0 = (fq << 4) ^ ((fm & 7) << 4);
    const int px1 = (64 | (fq << 4)) ^ ((fm & 7) << 4);
    const char* Lar = L + wm * 16384 + prow;
    const char* Lbr = L + 65536 + (wn >> 1) * 16384 + (wn & 1) * 8192 + prow;

    f32x4 acc[8][4] = {};
    bf16x8 a_[2][2], b_[4][2];

#define ST_A(sbuf, hh, t) do { \
    const char* s_ = Ab + (size_t)(hh) * 128 * lda2 + (size_t)(t) * 128 + offA; \
    gld_lds16(s_,             L + (sbuf) * 32768 + (hh) * 16384 + w * 1024); \
    gld_lds16(s_ + 64 * lda2, L + (sbuf) * 32768 + (hh) * 16384 + 8192 + w * 1024); \
  } while (0)
#define ST_B(sbuf, hh, t) do { \
    const char* s_ = Bb + (size_t)(hh) * 128 * ldb2 + (size_t)(t) * 128 + offB; \
    gld_lds16(s_,             L + 65536 + (sbuf) * 32768 + (hh) * 16384 + w * 1024); \
    gld_lds16(s_ + 64 * ldb2, L + 65536 + (sbuf) * 32768 + (hh) * 16384 + 8192 + w * 1024); \
  } while (0)
#define DS_A1(rb, q, kh) do { \
    a_[0][kh] = *(const bf16x8*)(Lar + (rb) * 32768 + ((q) * 32 +  0) * 128 + ((kh) ? px1 : px0)); \
    a_[1][kh] = *(const bf16x8*)(Lar + (rb) * 32768 + ((q) * 32 + 16) * 128 + ((kh) ? px1 : px0)); \
  } while (0)
#define DS_Bh(rb, kh) do { \
    _Pragma("unroll") \
    for (int ni = 0; ni < 4; ni++) \
      b_[ni][kh] = *(const bf16x8*)(Lbr + (rb) * 32768 + ni * 2048 + ((kh) ? px1 : px0)); \
  } while (0)
#define MFMA_H(q, kh) do { \
    _Pragma("unroll") \
    for (int mi = 0; mi < 2; mi++) \
      _Pragma("unroll") \
      for (int ni = 0; ni < 4; ni++) \
        acc[(q)*2+mi][ni] = __builtin_amdgcn_mfma_f32_16x16x32_bf16( \
            a_[mi][kh], b_[ni][kh], acc[(q)*2+mi][ni], 0, 0, 0); \
  } while (0)
#define PHASE(rb, q, rb2, q2, STAGE, DOVMC) do { \
    STAGE; \
    if (DOVMC) VMC4; \
    BARR; LGKM0; \
    __builtin_amdgcn_s_setprio(1); \
    MFMA_H(q, 0); \
    __builtin_amdgcn_s_setprio(0); \
    DS_A1(rb2, q2, 0); \
    if ((q) == 3) DS_Bh(rb2, 0); \
    SCHED0; \
    __builtin_amdgcn_s_setprio(1); \
    MFMA_H(q, 1); \
    __builtin_amdgcn_s_setprio(0); \
    DS_A1(rb2, q2, 1); \
    if ((q) == 3) DS_Bh(rb2, 1); \
    BARR; \
  } while (0)

    const int NT = K >> 6;               // K-tiles of 64 (NT even, >=2)
    ST_B(0, 0, 0); ST_B(0, 1, 0);
    ST_A(0, 0, 0); ST_A(0, 1, 0);
    ST_B(1, 0, 1); ST_B(1, 1, 1);
    VMC4;
    BARR;
    DS_Bh(0, 0); DS_Bh(0, 1);
    DS_A1(0, 0, 0); DS_A1(0, 0, 1);

    for (int t0 = 0; t0 < NT; t0 += 2) {
        const int tA1 = t0 + 1;
        const int tN2 = (t0 + 2 < NT) ? t0 + 2 : NT - 1;   // clamp: dead slot
        const int tN3 = (t0 + 3 < NT) ? t0 + 3 : NT - 1;
        // ---- K-tile t0 from buf0 ----
        PHASE(0, 0, 0, 1, ST_A(1, 0, tA1), 0);
        PHASE(0, 1, 0, 2, ST_A(1, 1, tA1), 0);
        PHASE(0, 2, 0, 3, ST_B(0, 0, tN2), 0);
        PHASE(0, 3, 1, 0, ST_B(0, 1, tN2), 1);
        // ---- K-tile t0+1 from buf1 ----
        PHASE(1, 0, 1, 1, ST_A(0, 0, tN2), 0);
        PHASE(1, 1, 1, 2, ST_A(0, 1, tN2), 0);
        PHASE(1, 2, 1, 3, ST_B(1, 0, tN3), 0);
        PHASE(1, 3, 0, 0, ST_B(1, 1, tN3), 1);
    }
    asm volatile("s_waitcnt vmcnt(0)" ::: "memory");  // drain DMA before exit

    #pragma unroll
    for (int i = 0; i < 8; i++) {
        #pragma unroll
        for (int ni = 0; ni < 4; ni++) {
            int n = n0 + wn * 64 + ni * 16 + fm;
            #pragma unroll
            for (int r = 0; r < 4; r++) {
                int m = m0 + wm * 128 + i * 16 + fq * 4 + r;
                float v = acc[i][ni][r];
                if (EPI == 2) v += aux[(size_t)m * ldc + n];
                st1(&C[(size_t)m * ldc + n], v);
            }
        }
    }
#undef ST_A
#undef ST_B
#undef DS_A1
#undef DS_Bh
#undef MFMA_H
#undef PHASE
}

// ============================================================================
// 256x128 variant (full-GPU grids for narrow N), same WAR-interleave.
// ============================================================================
template<int EPI, typename TC>
__global__ __launch_bounds__(512, 2) void gemm_8p_n128(
    const bf16* __restrict__ A, int lda,
    const bf16* __restrict__ B, int ldb,
    TC* __restrict__ C, int ldc,
    int K, const float* __restrict__ aux, int nbn)
{
    __shared__ bf16 lds[49152];          // 96 KB
    char* L = (char*)lds;
    const int tid = threadIdx.x;
    const int lane = tid & 63;
    const int w = tid >> 6;              // 0..7
    const int wm = w >> 1;               // 0..3
    const int wn = w & 1;                // 0..1

    int nwg = gridDim.x;
    int bid = blockIdx.x;
    int sb = bid;
    if ((nwg & 7) == 0) sb = (bid & 7) * (nwg >> 3) + (bid >> 3);
    const int m0 = (sb / nbn) * 256;
    const int n0 = (sb % nbn) * 128;

    const size_t lda2 = (size_t)lda * 2;
    const size_t ldb2 = (size_t)ldb * 2;
    const int l8 = lane >> 3;
    const int scol = ((lane & 7) ^ l8) << 4;
    const size_t offA = (size_t)(w * 8 + l8) * lda2 + scol;
    const size_t offB = (size_t)(w * 8 + l8) * ldb2 + scol;
    const char* Ab = (const char*)A + (size_t)m0 * lda2;
    const char* Bb = (const char*)B + (size_t)n0 * ldb2;

    const int fm = lane & 15, fq = lane >> 4;
    const int prow = fm * 128;
    const int px0 = (fq << 4) ^ ((fm & 7) << 4);
    const int px1 = (64 | (fq << 4)) ^ ((fm & 7) << 4);
    const char* Lar = L + wm * 8192 + prow;            // wm*64 rows * 128B
    const char* Lbr = L + 65536 + wn * 8192 + prow;    // wn*64 rows * 128B

    f32x4 acc[4][4] = {};
    bf16x8 a_[2], b_[4][2];

#define ST_A(sbuf, hh, t) do { \
    const char* s_ = Ab + (size_t)(hh) * 128 * lda2 + (size_t)(t) * 128 + offA; \
    gld_lds16(s_,             L + (sbuf) * 32768 + (hh) * 16384 + w * 1024); \
    gld_lds16(s_ + 64 * lda2, L + (sbuf) * 32768 + (hh) * 16384 + 8192 + w * 1024); \
  } while (0)
#define ST_B1(sbuf, hh, t) do { \
    const char* s_ = Bb + (size_t)(hh) * 64 * ldb2 + (size_t)(t) * 128 + offB; \
    gld_lds16(s_, L + 65536 + (sbuf) * 16384 + (hh) * 8192 + w * 1024); \
  } while (0)
#define DS_A1h(rb, q, kh) do { \
    a_[kh] = *(const bf16x8*)(Lar + (rb) * 32768 + ((q) * 16) * 128 + ((kh) ? px1 : px0)); \
  } while (0)
#define DS_Bh(rb, kh) do { \
    _Pragma("unroll") \
    for (int ni = 0; ni < 4; ni++) \
      b_[ni][kh] = *(const bf16x8*)(Lbr + (rb) * 16384 + ni * 2048 + ((kh) ? px1 : px0)); \
  } while (0)
#define MFMA_Hh(q, kh) do { \
    _Pragma("unroll") \
    for (int ni = 0; ni < 4; ni++) \
      acc[q][ni] = __builtin_amdgcn_mfma_f32_16x16x32_bf16( \
          a_[kh], b_[ni][kh], acc[q][ni], 0, 0, 0); \
  } while (0)
#define PHASE(rb, q, rb2, q2, STAGE, DOVMC) do { \
    STAGE; \
    if (DOVMC) VMC2; \
    BARR; LGKM0; \
    __builtin_amdgcn_s_setprio(1); \
    MFMA_Hh(q, 0); \
    __builtin_amdgcn_s_setprio(0); \
    DS_A1h(rb2, q2, 0); \
    if ((q) == 3) DS_Bh(rb2, 0); \
    SCHED0; \
    __builtin_amdgcn_s_setprio(1); \
    MFMA_Hh(q, 1); \
    __builtin_amdgcn_s_setprio(0); \
    DS_A1h(rb2, q2, 1); \
    if ((q) == 3) DS_Bh(rb2, 1); \
    BARR; \
  } while (0)

    const int NT = K >> 6;               // K-tiles of 64 (NT even, >=2)
    ST_B1(0, 0, 0); ST_B1(0, 1, 0);
    ST_A(0, 0, 0); ST_A(0, 1, 0);
    ST_B1(1, 0, 1); ST_B1(1, 1, 1);
    VMC2;
    BARR;
    DS_Bh(0, 0); DS_Bh(0, 1);
    DS_A1h(0, 0, 0); DS_A1h(0, 0, 1);

    for (int t0 = 0; t0 < NT; t0 += 2) {
        const int tA1 = t0 + 1;
        const int tN2 = (t0 + 2 < NT) ? t0 + 2 : NT - 1;   // clamp: dead slot
        const int tN3 = (t0 + 3 < NT) ? t0 + 3 : NT - 1;
        // ---- K-tile t0 from buf0 ----
        PHASE(0, 0, 0, 1, ST_A(1, 0, tA1), 0);
        PHASE(0, 1, 0, 2, ST_A(1, 1, tA1), 0);
        PHASE(0, 2, 0, 3, ST_B1(0, 0, tN2), 0);
        PHASE(0, 3, 1, 0, ST_B1(0, 1, tN2), 1);
        // ---- K-tile t0+1 from buf1 ----
        PHASE(1, 0, 1, 1, ST_A(0, 0, tN2), 0);
        PHASE(1, 1, 1, 2, ST_A(0, 1, tN2), 0);
        PHASE(1, 2, 1, 3, ST_B1(1, 0, tN3), 0);
        PHASE(1, 3, 0, 0, ST_B1(1, 1, tN3), 1);
    }
    asm volatile("s_waitcnt vmcnt(0)" ::: "memory");

    #pragma unroll
    for (int i = 0; i < 4; i++) {
        #pragma unroll
        for (int ni = 0; ni < 4; ni++) {
            int n = n0 + wn * 64 + ni * 16 + fm;
            #pragma unroll
            for (int r = 0; r < 4; r++) {
                int m = m0 + wm * 64 + i * 16 + fq * 4 + r;
                float v = acc[i][ni][r];
                if (EPI == 2) v += aux[(size_t)m * ldc + n];
                st1(&C[(size_t)m * ldc + n], v);
            }
        }
    }
#undef ST_A
#undef ST_B1
#undef DS_A1h
#undef DS_Bh
#undef MFMA_Hh
#undef PHASE
}

// ---------------- MFMA bf16 GEMM, NT (128x128, used for dt-GEMM K=64) --------
template<int EPI, typename TC>
__global__ __launch_bounds__(256) void gemm_mfma(
    const bf16* __restrict__ A, int lda,
    const bf16* __restrict__ B, int ldb,
    TC* __restrict__ C, int ldc,
    int K, const float* __restrict__ aux)
{
    __shared__ bf16 As[128 * 32];
    __shared__ bf16 Bs[128 * 32];
    const int tid = threadIdx.x;
    const int lane = tid & 63;
    const int w = tid >> 6;
    const int wm = w >> 1, wn = w & 1;
    const int m0 = blockIdx.y * 128, n0 = blockIdx.x * 128;

    const int srow = lane >> 2;
    const int schunk = (lane & 3) * 8;

    const int fm = lane & 15;
    const int fq = lane >> 4;

    f32x4 acc[4][4] = {};

    for (int kt = 0; kt < K; kt += 32) {
        #pragma unroll
        for (int i = 0; i < 2; i++) {
            int r0 = i * 64 + w * 16;
            gld_lds16(A + (size_t)(m0 + r0 + srow) * lda + kt + schunk, &As[r0 * 32]);
            gld_lds16(B + (size_t)(n0 + r0 + srow) * ldb + kt + schunk, &Bs[r0 * 32]);
        }
        __syncthreads();
        bf16x8 af[4], bfr[4];
        #pragma unroll
        for (int i = 0; i < 4; i++) {
            af[i]  = *(const bf16x8*)&As[(wm * 64 + i * 16 + fm) * 32 + fq * 8];
            bfr[i] = *(const bf16x8*)&Bs[(wn * 64 + i * 16 + fm) * 32 + fq * 8];
        }
        #pragma unroll
        for (int i = 0; i < 4; i++)
            #pragma unroll
            for (int j = 0; j < 4; j++)
                acc[i][j] = __builtin_amdgcn_mfma_f32_16x16x32_bf16(
                    af[i], bfr[j], acc[i][j], 0, 0, 0);
        __syncthreads();
    }

    #pragma unroll
    for (int i = 0; i < 4; i++) {
        #pragma unroll
        for (int r = 0; r < 4; r++) {
            int m = m0 + wm * 64 + i * 16 + fq * 4 + r;
            #pragma unroll
            for (int j = 0; j < 4; j++) {
                int n = n0 + wn * 64 + j * 16 + fm;
                float v = acc[i][j][r];
                if (EPI == 1) {
                    v = softplus_fast(v + aux[n]);
                } else if (EPI == 2) {
                    v += aux[(size_t)m * ldc + n];
                }
                st1(&C[(size_t)m * ldc + n], v);
            }
        }
    }
}

// ---------------- x_proj MFMA: xdbl[R,96] = xc[R,DI] @ W_x[96,DI]^T ----------
__global__ __launch_bounds__(256) void xproj_mfma(
    const bf16* __restrict__ A,      // xc [R, DI]
    const bf16* __restrict__ Bm,     // W_x bf16, padded to 128 rows [128, DI]
    float* __restrict__ Cx,          // xdbl [R, 96]
    bf16* __restrict__ dtr)          // [R, 64]
{
    __shared__ bf16 As[32 * 32];
    __shared__ bf16 Bs[128 * 32];
    const int tid = threadIdx.x;
    const int lane = tid & 63;
    const int w = tid >> 6;
    const int wm = w >> 1, wn = w & 1;
    const int m0 = blockIdx.x * 32;
    const int srow = lane >> 2;
    const int schunk = (lane & 3) * 8;
    const int fm = lane & 15;
    const int fq = lane >> 4;
    f32x4 acc[3] = {};
    for (int kt = 0; kt < DI; kt += 32) {
        if (w < 2) {
            int r0 = w * 16;
            gld_lds16(A + (size_t)(m0 + r0 + srow) * DI + kt + schunk, &As[r0 * 32]);
        }
        {
            int r0 = w * 32;
            gld_lds16(Bm + (size_t)(r0 + srow) * DI + kt + schunk, &Bs[r0 * 32]);
            gld_lds16(Bm + (size_t)(r0 + 16 + srow) * DI + kt + schunk, &Bs[(r0 + 16) * 32]);
        }
        __syncthreads();
        bf16x8 af = *(const bf16x8*)&As[(wm * 16 + fm) * 32 + fq * 8];
        #pragma unroll
        for (int j = 0; j < 3; j++) {
            bf16x8 bf = *(const bf16x8*)&Bs[((wn * 3 + j) * 16 + fm) * 32 + fq * 8];
            acc[j] = __builtin_amdgcn_mfma_f32_16x16x32_bf16(af, bf, acc[j], 0, 0, 0);
        }
        __syncthreads();
    }
    #pragma unroll
    for (int j = 0; j < 3; j++) {
        int col = (wn * 3 + j) * 16 + fm;
        #pragma unroll
        for (int r = 0; r < 4; r++) {
            int m = m0 + wm * 16 + fq * 4 + r;
            float v = acc[j][r];
            Cx[(size_t)m * 96 + col] = v;
            if (col < 64) dtr[(size_t)m * 64 + col] = f2b(v);
        }
    }
}

// ---------------- Tiled f32-compute GEMM (fallback path only) ----------------
template<int EPI, typename TA, typename TB, typename TC>
__global__ __launch_bounds__(256) void gemm_nt(
    const TA* __restrict__ A, int lda,
    const TB* __restrict__ B, int ldb,
    TC* __restrict__ C, int ldc,
    int M, int N, int K,
    const float* __restrict__ aux)
{
    __shared__ float As[16][64];
    __shared__ float Bs[16][64];
    int tid = threadIdx.x;
    int m0 = blockIdx.y * 64, n0 = blockIdx.x * 64;
    int lr = tid >> 2;
    int lc = (tid & 3) * 4;
    int tm = tid >> 4;
    int tn = tid & 15;
    float acc[4][4] = {};
    for (int kt = 0; kt < K; kt += 16) {
        float4 av = ld4(A + (size_t)(m0 + lr) * lda + kt + lc);
        float4 bv = make_float4(0.f, 0.f, 0.f, 0.f);
        if (n0 + lr < N)
            bv = ld4(B + (size_t)(n0 + lr) * ldb + kt + lc);
        As[lc + 0][lr] = av.x; As[lc + 1][lr] = av.y;
        As[lc + 2][lr] = av.z; As[lc + 3][lr] = av.w;
        Bs[lc + 0][lr] = bv.x; Bs[lc + 1][lr] = bv.y;
        Bs[lc + 2][lr] = bv.z; Bs[lc + 3][lr] = bv.w;
        __syncthreads();
        #pragma unroll
        for (int k = 0; k < 16; k++) {
            float4 a4 = *(const float4*)&As[k][tm * 4];
            float4 b4 = *(const float4*)&Bs[k][tn * 4];
            float am[4] = {a4.x, a4.y, a4.z, a4.w};
            float bn[4] = {b4.x, b4.y, b4.z, b4.w};
            #pragma unroll
            for (int i = 0; i < 4; i++)
                #pragma unroll
                for (int j = 0; j < 4; j++)
                    acc[i][j] = fmaf(am[i], bn[j], acc[i][j]);
        }
        __syncthreads();
    }
    #pragma unroll
    for (int i = 0; i < 4; i++) {
        int m = m0 + tm * 4 + i;
        #pragma unroll
        for (int j = 0; j < 4; j++) {
            int n = n0 + tn * 4 + j;
            if (n >= N) continue;
            float v = acc[i][j];
            if (EPI == 1) {
                v = softplus_fast(v + aux[n]);
            }
            st1(&C[(size_t)m * ldc + n], v);
        }
    }
}

// ---------------- Depthwise causal conv (4 taps) + SiLU ----------------------
__global__ __launch_bounds__(256) void conv_silu_kernel(
    const bf16* __restrict__ xz, const bf16* __restrict__ cwt,
    const float* __restrict__ cb, bf16* __restrict__ xc)
{
    int idx = blockIdx.x * 256 + threadIdx.x;   // R*DI/8 threads
    int d8 = idx & (DI / 8 - 1);                // 0..255
    int bl = idx >> 8;                          // 0..8191
    int l = bl & (LL - 1);
    int d0 = d8 * 8;
    float4 b0 = *(const float4*)(cb + d0);
    float4 b1 = *(const float4*)(cb + d0 + 4);
    float acc[8] = {b0.x, b0.y, b0.z, b0.w, b1.x, b1.y, b1.z, b1.w};
    #pragma unroll
    for (int k = 0; k < 4; k++) {
        if (l - 3 + k < 0) continue;
        bf16x8 xv = *(const bf16x8*)(xz + (size_t)(bl - 3 + k) * (2 * DI) + d0);
        bf16x8 wv = *(const bf16x8*)(cwt + k * DI + d0);
        #pragma unroll
        for (int j = 0; j < 8; j++)
            acc[j] = fmaf(b2f((bf16)xv[j]), b2f((bf16)wv[j]), acc[j]);
    }
    bf16x8 o;
    #pragma unroll
    for (int j = 0; j < 8; j++)
        o[j] = (short)f2b(acc[j] / (1.f + __expf(-acc[j])));
    *(bf16x8*)(xc + (size_t)bl * DI + d0) = o;
}

// ---------------- Chunked selective scan, thread-per-channel -----------------
// dt/u/z: zero-reuse data -> direct per-lane coalesced global reads (no LDS).
// B,C: 256-way broadcast -> staged in LDS per TT rows (sBC).
// structured path: Ads[s] = (s+1)*Ads[0] (checked in-kernel per block) ->
// 1 exp + addition-chain tree (depth 4) per t. P once per chunk via sum(dt).
template<int NCC>
__global__ __launch_bounds__(256) void scan_part1(
    const float* __restrict__ xdbl, const bf16* __restrict__ dty,
    const bf16* __restrict__ xc, const float* __restrict__ A_log,
    float* __restrict__ P, float* __restrict__ S)
{
    __shared__ alignas(16) float sBC[TT][32];
    __shared__ int sflag;
    const int CH = LL / NCC;
    int bid = blockIdx.x;
    int cg = bid & 7;                 // DI/TCH = 8
    int c  = (bid >> 3) & (NCC - 1);
    int b  = (bid >> 3) / NCC;
    int d0 = cg * TCH;
    int tid = threadIdx.x;
    int w = tid >> 6, l = tid & 63;
    int brow = l >> 3, bcol = (l & 7) * 4;
    int d = d0 + tid;

    if (tid == 0) sflag = 0;
    float Ads[16];
    #pragma unroll
    for (int q = 0; q < 4; q++) {
        float4 a4 = *(const float4*)&A_log[(size_t)d * DS + q * 4];
        Ads[q*4+0] = -__expf(a4.x); Ads[q*4+1] = -__expf(a4.y);
        Ads[q*4+2] = -__expf(a4.z); Ads[q*4+3] = -__expf(a4.w);
    }
    const float A0 = Ads[0];
    int bad = 0;
    #pragma unroll
    for (int s = 1; s < 16; s++) {
        float tgt = (float)(s + 1) * A0;
        bad |= (fabsf(Ads[s] - tgt) > 1e-5f * fabsf(tgt) + 1e-30f) ? 1 : 0;
    }
    __syncthreads();
    if (bad) atomicOr(&sflag, 1);
    __syncthreads();
    const int structured = (sflag == 0);

    float h[16];
    #pragma unroll
    for (int s = 0; s < 16; s++) h[s] = 0.f;
    float dsum = 0.f;

    const size_t rowbase = (size_t)b * LL + c * CH;
    for (int t0 = 0; t0 < CH; t0 += TT) {
        if (w < 2)
            gld_lds16(xdbl + (rowbase + t0 + w * 8 + brow) * 96 + DTR + bcol,
                      &sBC[w * 8][0]);
        __syncthreads();
        #pragma unroll
        for (int t = 0; t < TT; t++) {
            size_t g = (rowbase + t0 + t) * DI + d;
            float dtv = b2f(dty[g]);
            float uv  = b2f(xc[g]);
            float tmp = dtv * uv;
            dsum += dtv;
            const float4* bc = (const float4*)&sBC[t][0];
            float4 B0 = bc[0], B1 = bc[1], B2 = bc[2], B3 = bc[3];
            float Bv[16] = {B0.x,B0.y,B0.z,B0.w, B1.x,B1.y,B1.z,B1.w,
                            B2.x,B2.y,B2.z,B2.w, B3.x,B3.y,B3.z,B3.w};
            if (structured) {
                float dA[16];
                dA_tree(__expf(dtv * A0), dA);
                #pragma unroll
                for (int s = 0; s < 16; s++)
                    h[s] = dA[s] * h[s] + tmp * Bv[s];
            } else {
                #pragma unroll
                for (int s = 0; s < 16; s++) {
                    float dA = __expf(dtv * Ads[s]);
                    h[s] = dA * h[s] + tmp * Bv[s];
                }
            }
        }
        __syncthreads();
    }
    // P[s] = prod_t exp(dtv_t*Ads[s]) = exp(Ads[s]*sum_t dtv_t)  (exact)
    size_t o = ((size_t)(b * NCC + c) * DI + d) * DS;
    #pragma unroll
    for (int q = 0; q < 4; q++) {
        float4 pv = make_float4(__expf(Ads[q*4+0]*dsum), __expf(Ads[q*4+1]*dsum),
                                __expf(Ads[q*4+2]*dsum), __expf(Ads[q*4+3]*dsum));
        *(float4*)&P[o + q*4] = pv;
        *(float4*)&S[o + q*4] = make_float4(h[q*4], h[q*4+1], h[q*4+2], h[q*4+3]);
    }
}

template<int NCC>
__global__ __launch_bounds__(256) void scan_combine(
    const float* __restrict__ P, float* __restrict__ S)
{
    int g = blockIdx.x * 256 + threadIdx.x;   // B*DI*DS threads
    int b = g >> 15;                          // DI*DS = 32768
    int rem = g & 32767;
    float h = 0.f;
    #pragma unroll
    for (int c = 0; c < NCC; c++) {
        size_t o = ((size_t)(b * NCC + c) << 15) + rem;
        float p = P[o], sv = S[o];
        S[o] = h;                             // h_in for chunk c
        h = p * h + sv;
    }
}

template<int NCC>
__global__ __launch_bounds__(256) void scan_part2(
    const float* __restrict__ xdbl, bf16* __restrict__ dty,
    const bf16* __restrict__ xc, const bf16* __restrict__ xz,
    const float* __restrict__ A_log, const float* __restrict__ Dp,
    const float* __restrict__ Hin)
{
    __shared__ alignas(16) float sBC[TT][32];
    __shared__ int sflag;
    const int CH = LL / NCC;
    int bid = blockIdx.x;
    int cg = bid & 7;
    int c  = (bid >> 3) & (NCC - 1);
    int b  = (bid >> 3) / NCC;
    int d0 = cg * TCH;
    int tid = threadIdx.x;
    int w = tid >> 6, l = tid & 63;
    int brow = l >> 3, bcol = (l & 7) * 4;
    int d = d0 + tid;

    if (tid == 0) sflag = 0;
    float Ads[16];
    #pragma unroll
    for (int q = 0; q < 4; q++) {
        float4 a4 = *(const float4*)&A_log[(size_t)d * DS + q * 4];
        Ads[q*4+0] = -__expf(a4.x); Ads[q*4+1] = -__expf(a4.y);
        Ads[q*4+2] = -__expf(a4.z); Ads[q*4+3] = -__expf(a4.w);
    }
    const float A0 = Ads[0];
    int bad = 0;
    #pragma unroll
    for (int s = 1; s < 16; s++) {
        float tgt = (float)(s + 1) * A0;
        bad |= (fabsf(Ads[s] - tgt) > 1e-5f * fabsf(tgt) + 1e-30f) ? 1 : 0;
    }
    __syncthreads();
    if (bad) atomicOr(&sflag, 1);
    __syncthreads();
    const int structured = (sflag == 0);

    float h[16];
    size_t ho = ((size_t)(b * NCC + c) * DI + d) * DS;
    #pragma unroll
    for (int q = 0; q < 4; q++) {
        float4 hv = *(const float4*)&Hin[ho + q*4];
        h[q*4] = hv.x; h[q*4+1] = hv.y; h[q*4+2] = hv.z; h[q*4+3] = hv.w;
    }
    float dpd = Dp[d];

    const size_t rowbase = (size_t)b * LL + c * CH;
    for (int t0 = 0; t0 < CH; t0 += TT) {
        if (w < 2)
            gld_lds16(xdbl + (rowbase + t0 + w * 8 + brow) * 96 + DTR + bcol,
                      &sBC[w * 8][0]);
        __syncthreads();
        #pragma unroll
        for (int t = 0; t < TT; t++) {
            size_t g = (rowbase + t0 + t) * DI + d;
            float dtv = b2f(dty[g]);
            float uv  = b2f(xc[g]);
            float zv  = b2f(xz[(rowbase + t0 + t) * (2 * DI) + DI + d]);
            float tmp = dtv * uv;
            const float4* bc = (const float4*)&sBC[t][0];
            float4 B0 = bc[0], B1 = bc[1], B2 = bc[2], B3 = bc[3];
            float4 C0 = bc[4], C1 = bc[5], C2 = bc[6], C3 = bc[7];
            float Bv[16] = {B0.x,B0.y,B0.z,B0.w, B1.x,B1.y,B1.z,B1.w,
                            B2.x,B2.y,B2.z,B2.w, B3.x,B3.y,B3.z,B3.w};
            float Cv[16] = {C0.x,C0.y,C0.z,C0.w, C1.x,C1.y,C1.z,C1.w,
                            C2.x,C2.y,C2.z,C2.w, C3.x,C3.y,C3.z,C3.w};
            float y0 = 0.f, y1 = 0.f;
            if (structured) {
                float dA[16];
                dA_tree(__expf(dtv * A0), dA);
                #pragma unroll
                for (int s = 0; s < 16; s++) {
                    h[s] = dA[s] * h[s] + tmp * Bv[s];
                    if (s & 1) y1 = fmaf(h[s], Cv[s], y1);
                    else       y0 = fmaf(h[s], Cv[s], y0);
                }
            } else {
                #pragma unroll
                for (int s = 0; s < 16; s++) {
                    float dA = __expf(dtv * Ads[s]);
                    h[s] = dA * h[s] + tmp * Bv[s];
                    if (s & 1) y1 = fmaf(h[s], Cv[s], y1);
                    else       y0 = fmaf(h[s], Cv[s], y0);
                }
            }
            float y = y0 + y1;
            float yo = (y + uv * dpd) * (zv / (1.f + __expf(-zv)));
            dty[g] = f2b(yo);   // same-thread same-address read->write: safe
        }
        __syncthreads();
    }
}

// ---------------- Monolithic scan (fallback when ws is small) ----------------
__global__ __launch_bounds__(256) void scan_mono(
    const float* __restrict__ xdbl, bf16* __restrict__ dty,
    const bf16* __restrict__ xc, const bf16* __restrict__ xz,
    const float* __restrict__ A_log, const float* __restrict__ Dp)
{
    const int TC = 64;
    int b = blockIdx.x >> 7;
    int dblk = blockIdx.x & 127;
    int d0 = dblk * 16;
    int tid = threadIdx.x;
    int s = tid & 15;
    int dg = tid >> 4;
    int d = d0 + dg;
    float Ads = -__expf(A_log[(size_t)d * DS + s]);
    float h = 0.f;
    __shared__ float sdt[TC][16], su[TC][16], sB[TC][16], sC[TC][16], sy[TC][16];
    const size_t rowbase = (size_t)b * LL;
    int wi = tid >> 2;
    int wj = (tid & 3) * 4;
    float4 dpv = *(const float4*)(Dp + d0 + wj);
    for (int t0 = 0; t0 < LL; t0 += TC) {
        {
            size_t g = (rowbase + t0 + wi) * (size_t)DI + d0 + wj;
            *(float4*)&sdt[wi][wj] = ld4(dty + g);
            *(float4*)&su[wi][wj]  = ld4(xc + g);
        }
        #pragma unroll
        for (int r = 0; r < 4; r++) {
            int i = (tid >> 4) + r * 16;
            size_t g = (rowbase + t0 + i) * 96;
            sB[i][s] = xdbl[g + DTR + s];
            sC[i][s] = xdbl[g + DTR + DS + s];
        }
        __syncthreads();
        for (int i = 0; i < TC; i++) {
            float dtv = sdt[i][dg];
            float dA = __expf(dtv * Ads);
            h = dA * h + dtv * su[i][dg] * sB[i][s];
            float yp = h * sC[i][s];
            yp += __shfl_xor(yp, 1);
            yp += __shfl_xor(yp, 2);
            yp += __shfl_xor(yp, 4);
            yp += __shfl_xor(yp, 8);
            if (s == 0) sy[i][dg] = yp;
        }
        __syncthreads();
        {
            size_t g  = (rowbase + t0 + wi) * (size_t)DI + d0 + wj;
            size_t gz = (rowbase + t0 + wi) * (size_t)(2 * DI) + DI + d0 + wj;
            float4 zv = ld4(xz + gz);
            float4 yv = *(const float4*)&sy[wi][wj];
            float4 uv = *(const float4*)&su[wi][wj];
            ushort4 o;
            o.x = f2b((yv.x + uv.x * dpv.x) * (zv.x / (1.f + __expf(-zv.x))));
            o.y = f2b((yv.y + uv.y * dpv.y) * (zv.y / (1.f + __expf(-zv.y))));
            o.z = f2b((yv.z + uv.z * dpv.z) * (zv.z / (1.f + __expf(-zv.z))));
            o.w = f2b((yv.w + uv.w * dpv.w) * (zv.w / (1.f + __expf(-zv.w))));
            *(ushort4*)(dty + g) = o;
        }
        __syncthreads();
    }
}

// ---------------- slow conv (fallback path: f32 weights, 4 ch/thread) --------
__global__ __launch_bounds__(256) void conv_silu_slow(
    const bf16* __restrict__ xz, const float* __restrict__ cw,
    const float* __restrict__ cb, bf16* __restrict__ xc)
{
    int idx = blockIdx.x * 256 + threadIdx.x;
    int d4 = idx & (DI / 4 - 1);
    int bl = idx >> 9;
    int l = bl & (LL - 1);
    int d0 = d4 * 4;
    float4 bias = *(const float4*)(cb + d0);
    float acc[4] = {bias.x, bias.y, bias.z, bias.w};
    #pragma unroll
    for (int k = 0; k < 4; k++) {
        if (l - 3 + k < 0) continue;
        float4 xv = ld4(xz + (size_t)(bl - 3 + k) * (2 * DI) + d0);
        acc[0] = fmaf(xv.x, cw[(d0 + 0) * 4 + k], acc[0]);
        acc[1] = fmaf(xv.y, cw[(d0 + 1) * 4 + k], acc[1]);
        acc[2] = fmaf(xv.z, cw[(d0 + 2) * 4 + k], acc[2]);
        acc[3] = fmaf(xv.w, cw[(d0 + 3) * 4 + k], acc[3]);
    }
    ushort4 o;
    o.x = f2b(acc[0] / (1.f + __expf(-acc[0])));
    o.y = f2b(acc[1] / (1.f + __expf(-acc[1])));
    o.z = f2b(acc[2] / (1.f + __expf(-acc[2])));
    o.w = f2b(acc[3] / (1.f + __expf(-acc[3])));
    *(ushort4*)(xc + (size_t)bl * DI + d0) = o;
}

// ---------------------------------------------------------------------------
extern "C" void kernel_launch(void* const* d_in, const int* in_sizes, int n_in,
                              void* d_out, int out_size, void* d_ws, size_t ws_size,
                              hipStream_t stream)
{
    const float* x      = (const float*)d_in[0];
    const float* ln_w   = (const float*)d_in[1];
    const float* ln_b   = (const float*)d_in[2];
    const float* W_in   = (const float*)d_in[3];
    const float* conv_w = (const float*)d_in[4];
    const float* conv_b = (const float*)d_in[5];
    const float* W_x    = (const float*)d_in[6];
    const float* W_dt   = (const float*)d_in[7];
    const float* b_dt   = (const float*)d_in[8];
    const float* A_log  = (const float*)d_in[9];
    const float* Dp     = (const float*)d_in[10];
    const float* W_out  = (const float*)d_in[11];
    float* out = (float*)d_out;

    const size_t R = (size_t)BB * LL;   // 8192 rows

    // ws: xz bf16 | dty bf16 | xdbl f32 | P,S f32 (NCC-sized) | W_x_b | W_dt_b
    //     | dtr bf16 | cwt bf16 | [W_out_b2 bf16 if room]
    bf16*  xz    = (bf16*)d_ws;                    // R * 2*DI
    bf16*  dty   = xz + R * 2 * DI;                // R * DI
    float* xdbl  = (float*)(dty + R * DI);         // R * 96
    float* Pbuf  = xdbl + R * 96;

    const size_t headB = (size_t)((char*)Pbuf - (char*)d_ws);
    const size_t tailB = (size_t)(128 * DI + DI * DTR + R * DTR + 4 * DI) * 2 + 64;
    const size_t psU   = (size_t)BB * DI * DS * 4;   // per-chunk P/S bytes
    int ncc = 16;
    if (ws_size >= headB + 2 * (64 * psU) + tailB) ncc = 64;
    else if (ws_size >= headB + 2 * (32 * psU) + tailB) ncc = 32;
    const size_t psB = (size_t)ncc * psU;

    float* Sbuf   = (float*)((char*)Pbuf + psB);
    bf16*  W_x_b  = (bf16*)((char*)Sbuf + psB);    // 128*DI (96 used)
    bf16*  W_dt_b = W_x_b + 128 * DI;              // DI * DTR
    bf16*  dtr    = W_dt_b + DI * DTR;             // R * DTR
    bf16*  cwt    = dtr + R * DTR;                 // 4 * DI
    bf16*  W_out_b2 = cwt + 4 * DI;                // DM * DI (optional)
    const size_t ws_need = (size_t)((char*)(cwt + 4 * DI) - (char*)d_ws);
    const bool fast = ws_size >= ws_need;
    const size_t ws_need_w = (size_t)((char*)(W_out_b2 + (size_t)DM * DI) - (char*)d_ws);
    const int dowout = (fast && ws_size >= ws_need_w) ? 1 : 0;

    bf16*  W_in_b  = dty;   // dead before dt-gemm writes dty
    bf16*  W_out_b = xz;    // late-convert fallback (z dead after scan)

    bf16* xn = (bf16*)d_out;
    bf16* xc = (bf16*)d_out;

    // 0+1. fused prologue: LayerNorm + all weight converts (1 launch)
    {
        int nb = BB * LL + 4096;                    // LN + W_in
        if (fast) nb += 192 + 128 + 8 + (dowout ? 2048 : 0);
        prep_kernel<<<nb, 256, 0, stream>>>(
            x, ln_w, ln_b, xn, W_in, W_in_b, W_x, W_x_b, W_dt, W_dt_b,
            conv_w, cwt, W_out, W_out_b2, fast ? 1 : 0, dowout);
    }

    // 2. in_proj (8-phase 256^2 MFMA, WAR-interleave): xz = xn @ W_in^T
    for (int half = 0; half < 2; half++) {
        gemm_8p<0, bf16><<<dim3(16 * 16), 512, 0, stream>>>(
            xn + (size_t)half * 4096 * DM, DM, W_in_b, DM,
            xz + (size_t)half * 4096 * (2 * DI), 2 * DI, DM, nullptr, 16);
    }

    if (fast) {
        // 3. conv + SiLU -> xc (8 ch/thread, tap-major bf16 weights)
        conv_silu_kernel<<<(int)(R * DI / 8 / 256), 256, 0, stream>>>(
            xz, cwt, conv_b, xc);
        // 4a. x_proj MFMA -> xdbl f32 + dtr bf16
        xproj_mfma<<<(int)(R / 32), 256, 0, stream>>>(xc, W_x_b, xdbl, dtr);
        // 4b. dt = softplus(dtr @ W_dt^T + b_dt) -> dty bf16 (MFMA, K=64)
        gemm_mfma<1, bf16><<<dim3(DI / 128, R / 128), 256, 0, stream>>>(
            dtr, DTR, W_dt_b, DTR, dty, DI, DTR, b_dt);
        // 5. chunked scan (NCC chunks)
        if (ncc == 64) {
            scan_part1<64><<<BB * 64 * (DI / TCH), 256, 0, stream>>>(
                xdbl, dty, xc, A_log, Pbuf, Sbuf);
            scan_combine<64><<<BB * DI * DS / 256, 256, 0, stream>>>(Pbuf, Sbuf);
            scan_part2<64><<<BB * 64 * (DI / TCH), 256, 0, stream>>>(
                xdbl, dty, xc, xz, A_log, Dp, Sbuf);
        } else if (ncc == 32) {
            scan_part1<32><<<BB * 32 * (DI / TCH), 256, 0, stream>>>(
                xdbl, dty, xc, A_log, Pbuf, Sbuf);
            scan_combine<32><<<BB * DI * DS / 256, 256, 0, stream>>>(Pbuf, Sbuf);
            scan_part2<32><<<BB * 32 * (DI / TCH), 256, 0, stream>>>(
                xdbl, dty, xc, xz, A_log, Dp, Sbuf);
        } else {
            scan_part1<16><<<BB * 16 * (DI / TCH), 256, 0, stream>>>(
                xdbl, dty, xc, A_log, Pbuf, Sbuf);
            scan_combine<16><<<BB * DI * DS / 256, 256, 0, stream>>>(Pbuf, Sbuf);
            scan_part2<16><<<BB * 16 * (DI / TCH), 256, 0, stream>>>(
                xdbl, dty, xc, xz, A_log, Dp, Sbuf);
        }
    } else {
        // fallback: slow conv + f32 small GEMMs + monolithic scan
        conv_silu_slow<<<(int)(R * DI / 4 / 256), 256, 0, stream>>>(
            xz, conv_w, conv_b, xc);
        gemm_nt<0><<<dim3(2, R / 64), 256, 0, stream>>>(
            xc, DI, W_x, DI, xdbl, 96, (int)R, 96, DI, nullptr);
        gemm_nt<1><<<dim3(DI / 64, R / 64), 256, 0, stream>>>(
            xdbl, 96, W_dt, DTR, dty, DI, (int)R, DI, DTR, b_dt);
        scan_mono<<<BB * (DI / 16), 256, 0, stream>>>(
            xdbl, dty, xc, xz, A_log, Dp);
    }

    // 5b. late W_out convert only if no dedicated buffer (z dead after scan)
    const bf16* W_out_use = dowout ? (const bf16*)W_out_b2 : (const bf16*)W_out_b;
    if (!dowout)
        f2b_kernel<<<(DM * DI / 4) / 256, 256, 0, stream>>>(W_out, W_out_b, DM * DI / 4);

    // 6. out_proj (8-phase 256x128 MFMA, full-GPU grid, WAR-interleave)
    gemm_8p_n128<2, float><<<dim3((int)(R / 256) * (DM / 128)), 512, 0, stream>>>(
        dty, DI, W_out_use, DI, out, DM, DI, x, DM / 128);
}

// Round 11
// 389.653 us; speedup vs baseline: 1.1128x; 1.1128x over previous
//
#include <hip/hip_runtime.h>
#include <math.h>

#define BB 4
#define LL 2048
#define DM 1024
#define DI 2048
#define DS 16
#define DTR 64
#define TCH 256          // channels per scan block
#define TT 16            // timesteps per staged tile

typedef unsigned short bf16;
typedef __attribute__((ext_vector_type(8))) short bf16x8;
typedef __attribute__((ext_vector_type(4))) float f32x4;
typedef __attribute__((ext_vector_type(2))) float f32x2;

__device__ inline float b2f(bf16 u) { return __uint_as_float(((unsigned)u) << 16); }
__device__ inline bf16 f2b(float f) {
    unsigned u = __float_as_uint(f);
    u += 0x7FFF + ((u >> 16) & 1);   // round-to-nearest-even
    return (bf16)(u >> 16);
}

__device__ inline float4 ld4(const float* p) { return *(const float4*)p; }
__device__ inline float4 ld4(const bf16* p) {
    ushort4 v = *(const ushort4*)p;
    return make_float4(b2f(v.x), b2f(v.y), b2f(v.z), b2f(v.w));
}
__device__ inline void st1(float* p, float v) { *p = v; }
__device__ inline void st1(bf16* p, float v) { *p = f2b(v); }

// cheap softplus: hw v_exp_f32/v_log_f32 (~8 VALU instrs); bf16-sufficient.
__device__ inline float softplus_fast(float v) {
    return (v > 15.f) ? v : __logf(1.f + __expf(v));
}

// async global->LDS, 16 bytes per lane; LDS dest = wave-uniform base + lane*16
__device__ inline void gld_lds16(const void* g, void* l) {
    __builtin_amdgcn_global_load_lds(
        (const __attribute__((address_space(1))) unsigned int*)g,
        (__attribute__((address_space(3))) unsigned int*)l, 16, 0, 0);
}

// dA2[i] = {c1^(2i+1), c1^(2i+2)}: 3 scalar + 7 packed muls, shallow deps.
// clang emits v_pk_mul_f32 for <2 x float> products on gfx950.
__device__ inline void dA2_tree(float c1, f32x2* dA2) {
    float c2 = c1 * c1;
    float c4 = c2 * c2;
    float c8 = c4 * c4;
    f32x2 c2v = {c2, c2};
    f32x2 c8v = {c8, c8};
    dA2[0] = (f32x2){c1, c2};
    dA2[1] = dA2[0] * c2v;     // c3,c4
    dA2[2] = dA2[1] * c2v;     // c5,c6
    dA2[3] = dA2[2] * c2v;     // c7,c8
    dA2[4] = dA2[0] * c8v;
    dA2[5] = dA2[1] * c8v;
    dA2[6] = dA2[2] * c8v;
    dA2[7] = dA2[3] * c8v;
}

// ---------------- f32 -> bf16 convert (late W_out fallback only) -------------
__global__ __launch_bounds__(256) void f2b_kernel(const float* __restrict__ in,
    bf16* __restrict__ out, int n4)
{
    int i = blockIdx.x * 256 + threadIdx.x;
    if (i >= n4) return;
    float4 v = *(const float4*)(in + (size_t)i * 4);
    ushort4 o = { f2b(v.x), f2b(v.y), f2b(v.z), f2b(v.w) };
    *(ushort4*)(out + (size_t)i * 4) = o;
}

// ---------------- Fused prologue: LayerNorm + all weight converts ------------
__global__ __launch_bounds__(256) void prep_kernel(
    const float* __restrict__ x, const float* __restrict__ lw,
    const float* __restrict__ lb, bf16* __restrict__ xn,
    const float* __restrict__ W_in, bf16* __restrict__ W_in_b,
    const float* __restrict__ W_x, bf16* __restrict__ W_x_b,
    const float* __restrict__ W_dt, bf16* __restrict__ W_dt_b,
    const float* __restrict__ cw, bf16* __restrict__ cwt,
    const float* __restrict__ W_out, bf16* __restrict__ W_out_b,
    int dofast, int dowout)
{
    int blk = blockIdx.x;
    int tid = threadIdx.x;
    if (blk < BB * LL) {                       // ---- LayerNorm row ----
        int row = blk;
        const float* xr = x + (size_t)row * DM;
        float4 v = *(const float4*)(xr + tid * 4);
        float s1 = v.x + v.y + v.z + v.w;
        float s2 = v.x * v.x + v.y * v.y + v.z * v.z + v.w * v.w;
        #pragma unroll
        for (int o = 32; o > 0; o >>= 1) {
            s1 += __shfl_xor(s1, o);
            s2 += __shfl_xor(s2, o);
        }
        __shared__ float r1[4], r2[4];
        __shared__ float smu, srs;
        int wv = tid >> 6;
        if ((tid & 63) == 0) { r1[wv] = s1; r2[wv] = s2; }
        __syncthreads();
        if (tid == 0) {
            float t1 = r1[0] + r1[1] + r1[2] + r1[3];
            float t2 = r2[0] + r2[1] + r2[2] + r2[3];
            float mu = t1 * (1.0f / DM);
            float var = t2 * (1.0f / DM) - mu * mu;
            smu = mu;
            srs = rsqrtf(var + 1e-5f);
        }
        __syncthreads();
        float mu = smu, rs = srs;
        float4 wv4 = *(const float4*)(lw + tid * 4);
        float4 bv4 = *(const float4*)(lb + tid * 4);
        ushort4 o;
        o.x = f2b((v.x - mu) * rs * wv4.x + bv4.x);
        o.y = f2b((v.y - mu) * rs * wv4.y + bv4.y);
        o.z = f2b((v.z - mu) * rs * wv4.z + bv4.z);
        o.w = f2b((v.w - mu) * rs * wv4.w + bv4.w);
        *(ushort4*)(xn + (size_t)row * DM + tid * 4) = o;
        return;
    }
    blk -= BB * LL;
    if (blk < 4096) {                          // ---- W_in f2b ----
        int i = blk * 256 + tid;
        float4 v = *(const float4*)(W_in + (size_t)i * 4);
        ushort4 o = { f2b(v.x), f2b(v.y), f2b(v.z), f2b(v.w) };
        *(ushort4*)(W_in_b + (size_t)i * 4) = o;
        return;
    }
    blk -= 4096;
    if (!dofast) return;
    if (blk < 192) {                           // ---- W_x f2b ----
        int i = blk * 256 + tid;
        float4 v = *(const float4*)(W_x + (size_t)i * 4);
        ushort4 o = { f2b(v.x), f2b(v.y), f2b(v.z), f2b(v.w) };
        *(ushort4*)(W_x_b + (size_t)i * 4) = o;
        return;
    }
    blk -= 192;
    if (blk < 128) {                           // ---- W_dt f2b ----
        int i = blk * 256 + tid;
        float4 v = *(const float4*)(W_dt + (size_t)i * 4);
        ushort4 o = { f2b(v.x), f2b(v.y), f2b(v.z), f2b(v.w) };
        *(ushort4*)(W_dt_b + (size_t)i * 4) = o;
        return;
    }
    blk -= 128;
    if (blk < 8) {                             // ---- conv weight transpose ----
        int d = blk * 256 + tid;
        float4 w = *(const float4*)(cw + d * 4);
        cwt[0 * DI + d] = f2b(w.x);
        cwt[1 * DI + d] = f2b(w.y);
        cwt[2 * DI + d] = f2b(w.z);
        cwt[3 * DI + d] = f2b(w.w);
        return;
    }
    blk -= 8;
    if (dowout && blk < 2048) {                // ---- W_out f2b ----
        int i = blk * 256 + tid;
        float4 v = *(const float4*)(W_out + (size_t)i * 4);
        ushort4 o = { f2b(v.x), f2b(v.y), f2b(v.z), f2b(v.w) };
        *(ushort4*)(W_out_b + (size_t)i * 4) = o;
    }
}

// ============================================================================
// 256x256 8-phase MFMA GEMM (NT), WAR-interleaved fragment prefetch.
// ============================================================================
#define BARR  do { asm volatile("" ::: "memory"); __builtin_amdgcn_s_barrier(); \
                   asm volatile("" ::: "memory"); } while (0)
#define LGKM0 do { asm volatile("s_waitcnt lgkmcnt(0)" ::: "memory"); \
                   __builtin_amdgcn_sched_barrier(0); } while (0)
#define VMC4  asm volatile("s_waitcnt vmcnt(4)" ::: "memory")
#define VMC2  asm volatile("s_waitcnt vmcnt(2)" ::: "memory")
#define SCHED0 __builtin_amdgcn_sched_barrier(0)

template<int EPI, typename TC>
__global__ __launch_bounds__(512, 2) void gemm_8p(
    const bf16* __restrict__ A, int lda,
    const bf16* __restrict__ B, int ldb,
    TC* __restrict__ C, int ldc,
    int K, const float* __restrict__ aux, int nbn)
{
    __shared__ bf16 lds[65536];          // 128 KB: A [0,64K) B [64K,128K)
    char* L = (char*)lds;
    const int tid = threadIdx.x;
    const int lane = tid & 63;
    const int w = tid >> 6;              // 0..7
    const int wm = w >> 2;               // 0..1
    const int wn = w & 3;                // 0..3

    int nwg = gridDim.x;
    int bid = blockIdx.x;
    int sb = bid;
    if ((nwg & 7) == 0) sb = (bid & 7) * (nwg >> 3) + (bid >> 3);
    const int m0 = (sb / nbn) * 256;
    const int n0 = (sb % nbn) * 256;

    const size_t lda2 = (size_t)lda * 2;
    const size_t ldb2 = (size_t)ldb * 2;
    const int l8 = lane >> 3;
    const int scol = ((lane & 7) ^ l8) << 4;
    const size_t offA = (size_t)(w * 8 + l8) * lda2 + scol;
    const size_t offB = (size_t)(w * 8 + l8) * ldb2 + scol;
    const char* Ab = (const char*)A + (size_t)m0 * lda2;
    const char* Bb = (const char*)B + (size_t)n0 * ldb2;

    const int fm = lane & 15, fq = lane >> 4;
    const int prow = fm * 128;
    const int px0 = (fq << 4) ^ ((fm & 7) << 4);
    const int px1 = (64 | (fq << 4)) ^ ((fm & 7) << 4);
    const char* Lar = L + wm * 16384 + prow;
    const char* Lbr = L + 65536 + (wn >> 1) * 16384 + (wn & 1) * 8192 + prow;

    f32x4 acc[8][4] = {};
    bf16x8 a_[2][2], b_[4][2];

#define ST_A(sbuf, hh, t) do { \
    const char* s_ = Ab + (size_t)(hh) * 128 * lda2 + (size_t)(t) * 128 + offA; \
    gld_lds16(s_,             L + (sbuf) * 32768 + (hh) * 16384 + w * 1024); \
    gld_lds16(s_ + 64 * lda2, L + (sbuf) * 32768 + (hh) * 16384 + 8192 + w * 1024); \
  } while (0)
#define ST_B(sbuf, hh, t) do { \
    const char* s_ = Bb + (size_t)(hh) * 128 * ldb2 + (size_t)(t) * 128 + offB; \
    gld_lds16(s_,             L + 65536 + (sbuf) * 32768 + (hh) * 16384 + w * 1024); \
    gld_lds16(s_ + 64 * ldb2, L + 65536 + (sbuf) * 32768 + (hh) * 16384 + 8192 + w * 1024); \
  } while (0)
#define DS_A1(rb, q, kh) do { \
    a_[0][kh] = *(const bf16x8*)(Lar + (rb) * 32768 + ((q) * 32 +  0) * 128 + ((kh) ? px1 : px0)); \
    a_[1][kh] = *(const bf16x8*)(Lar + (rb) * 32768 + ((q) * 32 + 16) * 128 + ((kh) ? px1 : px0)); \
  } while (0)
#define DS_Bh(rb, kh) do { \
    _Pragma("unroll") \
    for (int ni = 0; ni < 4; ni++) \
      b_[ni][kh] = *(const bf16x8*)(Lbr + (rb) * 32768 + ni * 2048 + ((kh) ? px1 : px0)); \
  } while (0)
#define MFMA_H(q, kh) do { \
    _Pragma("unroll") \
    for (int mi = 0; mi < 2; mi++) \
      _Pragma("unroll") \
      for (int ni = 0; ni < 4; ni++) \
        acc[(q)*2+mi][ni] = __builtin_amdgcn_mfma_f32_16x16x32_bf16( \
            a_[mi][kh], b_[ni][kh], acc[(q)*2+mi][ni], 0, 0, 0); \
  } while (0)
#define PHASE(rb, q, rb2, q2, STAGE, DOVMC) do { \
    STAGE; \
    if (DOVMC) VMC4; \
    BARR; LGKM0; \
    __builtin_amdgcn_s_setprio(1); \
    MFMA_H(q, 0); \
    __builtin_amdgcn_s_setprio(0); \
    DS_A1(rb2, q2, 0); \
    if ((q) == 3) DS_Bh(rb2, 0); \
    SCHED0; \
    __builtin_amdgcn_s_setprio(1); \
    MFMA_H(q, 1); \
    __builtin_amdgcn_s_setprio(0); \
    DS_A1(rb2, q2, 1); \
    if ((q) == 3) DS_Bh(rb2, 1); \
    BARR; \
  } while (0)

    const int NT = K >> 6;               // K-tiles of 64 (NT even, >=2)
    ST_B(0, 0, 0); ST_B(0, 1, 0);
    ST_A(0, 0, 0); ST_A(0, 1, 0);
    ST_B(1, 0, 1); ST_B(1, 1, 1);
    VMC4;
    BARR;
    DS_Bh(0, 0); DS_Bh(0, 1);
    DS_A1(0, 0, 0); DS_A1(0, 0, 1);

    for (int t0 = 0; t0 < NT; t0 += 2) {
        const int tA1 = t0 + 1;
        const int tN2 = (t0 + 2 < NT) ? t0 + 2 : NT - 1;   // clamp: dead slot
        const int tN3 = (t0 + 3 < NT) ? t0 + 3 : NT - 1;
        // ---- K-tile t0 from buf0 ----
        PHASE(0, 0, 0, 1, ST_A(1, 0, tA1), 0);
        PHASE(0, 1, 0, 2, ST_A(1, 1, tA1), 0);
        PHASE(0, 2, 0, 3, ST_B(0, 0, tN2), 0);
        PHASE(0, 3, 1, 0, ST_B(0, 1, tN2), 1);
        // ---- K-tile t0+1 from buf1 ----
        PHASE(1, 0, 1, 1, ST_A(0, 0, tN2), 0);
        PHASE(1, 1, 1, 2, ST_A(0, 1, tN2), 0);
        PHASE(1, 2, 1, 3, ST_B(1, 0, tN3), 0);
        PHASE(1, 3, 0, 0, ST_B(1, 1, tN3), 1);
    }
    asm volatile("s_waitcnt vmcnt(0)" ::: "memory");  // drain DMA before exit

    #pragma unroll
    for (int i = 0; i < 8; i++) {
        #pragma unroll
        for (int ni = 0; ni < 4; ni++) {
            int n = n0 + wn * 64 + ni * 16 + fm;
            #pragma unroll
            for (int r = 0; r < 4; r++) {
                int m = m0 + wm * 128 + i * 16 + fq * 4 + r;
                float v = acc[i][ni][r];
                if (EPI == 2) v += aux[(size_t)m * ldc + n];
                st1(&C[(size_t)m * ldc + n], v);
            }
        }
    }
#undef ST_A
#undef ST_B
#undef DS_A1
#undef DS_Bh
#undef MFMA_H
#undef PHASE
}

// ============================================================================
// 256x128 variant (full-GPU grids for narrow N), same WAR-interleave.
// ============================================================================
template<int EPI, typename TC>
__global__ __launch_bounds__(512, 2) void gemm_8p_n128(
    const bf16* __restrict__ A, int lda,
    const bf16* __restrict__ B, int ldb,
    TC* __restrict__ C, int ldc,
    int K, const float* __restrict__ aux, int nbn)
{
    __shared__ bf16 lds[49152];          // 96 KB
    char* L = (char*)lds;
    const int tid = threadIdx.x;
    const int lane = tid & 63;
    const int w = tid >> 6;              // 0..7
    const int wm = w >> 1;               // 0..3
    const int wn = w & 1;                // 0..1

    int nwg = gridDim.x;
    int bid = blockIdx.x;
    int sb = bid;
    if ((nwg & 7) == 0) sb = (bid & 7) * (nwg >> 3) + (bid >> 3);
    const int m0 = (sb / nbn) * 256;
    const int n0 = (sb % nbn) * 128;

    const size_t lda2 = (size_t)lda * 2;
    const size_t ldb2 = (size_t)ldb * 2;
    const int l8 = lane >> 3;
    const int scol = ((lane & 7) ^ l8) << 4;
    const size_t offA = (size_t)(w * 8 + l8) * lda2 + scol;
    const size_t offB = (size_t)(w * 8 + l8) * ldb2 + scol;
    const char* Ab = (const char*)A + (size_t)m0 * lda2;
    const char* Bb = (const char*)B + (size_t)n0 * ldb2;

    const int fm = lane & 15, fq = lane >> 4;
    const int prow = fm * 128;
    const int px0 = (fq << 4) ^ ((fm & 7) << 4);
    const int px1 = (64 | (fq << 4)) ^ ((fm & 7) << 4);
    const char* Lar = L + wm * 8192 + prow;            // wm*64 rows * 128B
    const char* Lbr = L + 65536 + wn * 8192 + prow;    // wn*64 rows * 128B

    f32x4 acc[4][4] = {};
    bf16x8 a_[2], b_[4][2];

#define ST_A(sbuf, hh, t) do { \
    const char* s_ = Ab + (size_t)(hh) * 128 * lda2 + (size_t)(t) * 128 + offA; \
    gld_lds16(s_,             L + (sbuf) * 32768 + (hh) * 16384 + w * 1024); \
    gld_lds16(s_ + 64 * lda2, L + (sbuf) * 32768 + (hh) * 16384 + 8192 + w * 1024); \
  } while (0)
#define ST_B1(sbuf, hh, t) do { \
    const char* s_ = Bb + (size_t)(hh) * 64 * ldb2 + (size_t)(t) * 128 + offB; \
    gld_lds16(s_, L + 65536 + (sbuf) * 16384 + (hh) * 8192 + w * 1024); \
  } while (0)
#define DS_A1h(rb, q, kh) do { \
    a_[kh] = *(const bf16x8*)(Lar + (rb) * 32768 + ((q) * 16) * 128 + ((kh) ? px1 : px0)); \
  } while (0)
#define DS_Bh(rb, kh) do { \
    _Pragma("unroll") \
    for (int ni = 0; ni < 4; ni++) \
      b_[ni][kh] = *(const bf16x8*)(Lbr + (rb) * 16384 + ni * 2048 + ((kh) ? px1 : px0)); \
  } while (0)
#define MFMA_Hh(q, kh) do { \
    _Pragma("unroll") \
    for (int ni = 0; ni < 4; ni++) \
      acc[q][ni] = __builtin_amdgcn_mfma_f32_16x16x32_bf16( \
          a_[kh], b_[ni][kh], acc[q][ni], 0, 0, 0); \
  } while (0)
#define PHASE(rb, q, rb2, q2, STAGE, DOVMC) do { \
    STAGE; \
    if (DOVMC) VMC2; \
    BARR; LGKM0; \
    __builtin_amdgcn_s_setprio(1); \
    MFMA_Hh(q, 0); \
    __builtin_amdgcn_s_setprio(0); \
    DS_A1h(rb2, q2, 0); \
    if ((q) == 3) DS_Bh(rb2, 0); \
    SCHED0; \
    __builtin_amdgcn_s_setprio(1); \
    MFMA_Hh(q, 1); \
    __builtin_amdgcn_s_setprio(0); \
    DS_A1h(rb2, q2, 1); \
    if ((q) == 3) DS_Bh(rb2, 1); \
    BARR; \
  } while (0)

    const int NT = K >> 6;               // K-tiles of 64 (NT even, >=2)
    ST_B1(0, 0, 0); ST_B1(0, 1, 0);
    ST_A(0, 0, 0); ST_A(0, 1, 0);
    ST_B1(1, 0, 1); ST_B1(1, 1, 1);
    VMC2;
    BARR;
    DS_Bh(0, 0); DS_Bh(0, 1);
    DS_A1h(0, 0, 0); DS_A1h(0, 0, 1);

    for (int t0 = 0; t0 < NT; t0 += 2) {
        const int tA1 = t0 + 1;
        const int tN2 = (t0 + 2 < NT) ? t0 + 2 : NT - 1;   // clamp: dead slot
        const int tN3 = (t0 + 3 < NT) ? t0 + 3 : NT - 1;
        // ---- K-tile t0 from buf0 ----
        PHASE(0, 0, 0, 1, ST_A(1, 0, tA1), 0);
        PHASE(0, 1, 0, 2, ST_A(1, 1, tA1), 0);
        PHASE(0, 2, 0, 3, ST_B1(0, 0, tN2), 0);
        PHASE(0, 3, 1, 0, ST_B1(0, 1, tN2), 1);
        // ---- K-tile t0+1 from buf1 ----
        PHASE(1, 0, 1, 1, ST_A(0, 0, tN2), 0);
        PHASE(1, 1, 1, 2, ST_A(0, 1, tN2), 0);
        PHASE(1, 2, 1, 3, ST_B1(1, 0, tN3), 0);
        PHASE(1, 3, 0, 0, ST_B1(1, 1, tN3), 1);
    }
    asm volatile("s_waitcnt vmcnt(0)" ::: "memory");

    #pragma unroll
    for (int i = 0; i < 4; i++) {
        #pragma unroll
        for (int ni = 0; ni < 4; ni++) {
            int n = n0 + wn * 64 + ni * 16 + fm;
            #pragma unroll
            for (int r = 0; r < 4; r++) {
                int m = m0 + wm * 64 + i * 16 + fq * 4 + r;
                float v = acc[i][ni][r];
                if (EPI == 2) v += aux[(size_t)m * ldc + n];
                st1(&C[(size_t)m * ldc + n], v);
            }
        }
    }
#undef ST_A
#undef ST_B1
#undef DS_A1h
#undef DS_Bh
#undef MFMA_Hh
#undef PHASE
}

// ---------------- MFMA bf16 GEMM, NT (128x128, used for dt-GEMM K=64) --------
template<int EPI, typename TC>
__global__ __launch_bounds__(256) void gemm_mfma(
    const bf16* __restrict__ A, int lda,
    const bf16* __restrict__ B, int ldb,
    TC* __restrict__ C, int ldc,
    int K, const float* __restrict__ aux)
{
    __shared__ bf16 As[128 * 32];
    __shared__ bf16 Bs[128 * 32];
    const int tid = threadIdx.x;
    const int lane = tid & 63;
    const int w = tid >> 6;
    const int wm = w >> 1, wn = w & 1;
    const int m0 = blockIdx.y * 128, n0 = blockIdx.x * 128;

    const int srow = lane >> 2;
    const int schunk = (lane & 3) * 8;

    const int fm = lane & 15;
    const int fq = lane >> 4;

    f32x4 acc[4][4] = {};

    for (int kt = 0; kt < K; kt += 32) {
        #pragma unroll
        for (int i = 0; i < 2; i++) {
            int r0 = i * 64 + w * 16;
            gld_lds16(A + (size_t)(m0 + r0 + srow) * lda + kt + schunk, &As[r0 * 32]);
            gld_lds16(B + (size_t)(n0 + r0 + srow) * ldb + kt + schunk, &Bs[r0 * 32]);
        }
        __syncthreads();
        bf16x8 af[4], bfr[4];
        #pragma unroll
        for (int i = 0; i < 4; i++) {
            af[i]  = *(const bf16x8*)&As[(wm * 64 + i * 16 + fm) * 32 + fq * 8];
            bfr[i] = *(const bf16x8*)&Bs[(wn * 64 + i * 16 + fm) * 32 + fq * 8];
        }
        #pragma unroll
        for (int i = 0; i < 4; i++)
            #pragma unroll
            for (int j = 0; j < 4; j++)
                acc[i][j] = __builtin_amdgcn_mfma_f32_16x16x32_bf16(
                    af[i], bfr[j], acc[i][j], 0, 0, 0);
        __syncthreads();
    }

    #pragma unroll
    for (int i = 0; i < 4; i++) {
        #pragma unroll
        for (int r = 0; r < 4; r++) {
            int m = m0 + wm * 64 + i * 16 + fq * 4 + r;
            #pragma unroll
            for (int j = 0; j < 4; j++) {
                int n = n0 + wn * 64 + j * 16 + fm;
                float v = acc[i][j][r];
                if (EPI == 1) {
                    v = softplus_fast(v + aux[n]);
                } else if (EPI == 2) {
                    v += aux[(size_t)m * ldc + n];
                }
                st1(&C[(size_t)m * ldc + n], v);
            }
        }
    }
}

// ---------------- x_proj MFMA: xdbl[R,96] = xc[R,DI] @ W_x[96,DI]^T ----------
__global__ __launch_bounds__(256) void xproj_mfma(
    const bf16* __restrict__ A,      // xc [R, DI]
    const bf16* __restrict__ Bm,     // W_x bf16, padded to 128 rows [128, DI]
    float* __restrict__ Cx,          // xdbl [R, 96]
    bf16* __restrict__ dtr)          // [R, 64]
{
    __shared__ bf16 As[32 * 32];
    __shared__ bf16 Bs[128 * 32];
    const int tid = threadIdx.x;
    const int lane = tid & 63;
    const int w = tid >> 6;
    const int wm = w >> 1, wn = w & 1;
    const int m0 = blockIdx.x * 32;
    const int srow = lane >> 2;
    const int schunk = (lane & 3) * 8;
    const int fm = lane & 15;
    const int fq = lane >> 4;
    f32x4 acc[3] = {};
    for (int kt = 0; kt < DI; kt += 32) {
        if (w < 2) {
            int r0 = w * 16;
            gld_lds16(A + (size_t)(m0 + r0 + srow) * DI + kt + schunk, &As[r0 * 32]);
        }
        {
            int r0 = w * 32;
            gld_lds16(Bm + (size_t)(r0 + srow) * DI + kt + schunk, &Bs[r0 * 32]);
            gld_lds16(Bm + (size_t)(r0 + 16 + srow) * DI + kt + schunk, &Bs[(r0 + 16) * 32]);
        }
        __syncthreads();
        bf16x8 af = *(const bf16x8*)&As[(wm * 16 + fm) * 32 + fq * 8];
        #pragma unroll
        for (int j = 0; j < 3; j++) {
            bf16x8 bf = *(const bf16x8*)&Bs[((wn * 3 + j) * 16 + fm) * 32 + fq * 8];
            acc[j] = __builtin_amdgcn_mfma_f32_16x16x32_bf16(af, bf, acc[j], 0, 0, 0);
        }
        __syncthreads();
    }
    #pragma unroll
    for (int j = 0; j < 3; j++) {
        int col = (wn * 3 + j) * 16 + fm;
        #pragma unroll
        for (int r = 0; r < 4; r++) {
            int m = m0 + wm * 16 + fq * 4 + r;
            float v = acc[j][r];
            Cx[(size_t)m * 96 + col] = v;
            if (col < 64) dtr[(size_t)m * 64 + col] = f2b(v);
        }
    }
}

// ---------------- Tiled f32-compute GEMM (fallback path only) ----------------
template<int EPI, typename TA, typename TB, typename TC>
__global__ __launch_bounds__(256) void gemm_nt(
    const TA* __restrict__ A, int lda,
    const TB* __restrict__ B, int ldb,
    TC* __restrict__ C, int ldc,
    int M, int N, int K,
    const float* __restrict__ aux)
{
    __shared__ float As[16][64];
    __shared__ float Bs[16][64];
    int tid = threadIdx.x;
    int m0 = blockIdx.y * 64, n0 = blockIdx.x * 64;
    int lr = tid >> 2;
    int lc = (tid & 3) * 4;
    int tm = tid >> 4;
    int tn = tid & 15;
    float acc[4][4] = {};
    for (int kt = 0; kt < K; kt += 16) {
        float4 av = ld4(A + (size_t)(m0 + lr) * lda + kt + lc);
        float4 bv = make_float4(0.f, 0.f, 0.f, 0.f);
        if (n0 + lr < N)
            bv = ld4(B + (size_t)(n0 + lr) * ldb + kt + lc);
        As[lc + 0][lr] = av.x; As[lc + 1][lr] = av.y;
        As[lc + 2][lr] = av.z; As[lc + 3][lr] = av.w;
        Bs[lc + 0][lr] = bv.x; Bs[lc + 1][lr] = bv.y;
        Bs[lc + 2][lr] = bv.z; Bs[lc + 3][lr] = bv.w;
        __syncthreads();
        #pragma unroll
        for (int k = 0; k < 16; k++) {
            float4 a4 = *(const float4*)&As[k][tm * 4];
            float4 b4 = *(const float4*)&Bs[k][tn * 4];
            float am[4] = {a4.x, a4.y, a4.z, a4.w};
            float bn[4] = {b4.x, b4.y, b4.z, b4.w};
            #pragma unroll
            for (int i = 0; i < 4; i++)
                #pragma unroll
                for (int j = 0; j < 4; j++)
                    acc[i][j] = fmaf(am[i], bn[j], acc[i][j]);
        }
        __syncthreads();
    }
    #pragma unroll
    for (int i = 0; i < 4; i++) {
        int m = m0 + tm * 4 + i;
        #pragma unroll
        for (int j = 0; j < 4; j++) {
            int n = n0 + tn * 4 + j;
            if (n >= N) continue;
            float v = acc[i][j];
            if (EPI == 1) {
                v = softplus_fast(v + aux[n]);
            }
            st1(&C[(size_t)m * ldc + n], v);
        }
    }
}

// ---------------- Depthwise causal conv (4 taps) + SiLU ----------------------
__global__ __launch_bounds__(256) void conv_silu_kernel(
    const bf16* __restrict__ xz, const bf16* __restrict__ cwt,
    const float* __restrict__ cb, bf16* __restrict__ xc)
{
    int idx = blockIdx.x * 256 + threadIdx.x;   // R*DI/8 threads
    int d8 = idx & (DI / 8 - 1);                // 0..255
    int bl = idx >> 8;                          // 0..8191
    int l = bl & (LL - 1);
    int d0 = d8 * 8;
    float4 b0 = *(const float4*)(cb + d0);
    float4 b1 = *(const float4*)(cb + d0 + 4);
    float acc[8] = {b0.x, b0.y, b0.z, b0.w, b1.x, b1.y, b1.z, b1.w};
    #pragma unroll
    for (int k = 0; k < 4; k++) {
        if (l - 3 + k < 0) continue;
        bf16x8 xv = *(const bf16x8*)(xz + (size_t)(bl - 3 + k) * (2 * DI) + d0);
        bf16x8 wv = *(const bf16x8*)(cwt + k * DI + d0);
        #pragma unroll
        for (int j = 0; j < 8; j++)
            acc[j] = fmaf(b2f((bf16)xv[j]), b2f((bf16)wv[j]), acc[j]);
    }
    bf16x8 o;
    #pragma unroll
    for (int j = 0; j < 8; j++)
        o[j] = (short)f2b(acc[j] / (1.f + __expf(-acc[j])));
    *(bf16x8*)(xc + (size_t)bl * DI + d0) = o;
}

// ---------------- Chunked selective scan, thread-per-channel -----------------
// R7 memory layout (measured best): dt/u/z staged in LDS per TT rows, B/C
// broadcast staged in sBC. Structured path computes with float2-PACKED state
// (v_pk_fma_f32 / v_pk_mul_f32) to halve VALU issue count.
template<int NCC>
__global__ __launch_bounds__(256) void scan_part1(
    const float* __restrict__ xdbl, const bf16* __restrict__ dty,
    const bf16* __restrict__ xc, const float* __restrict__ A_log,
    float* __restrict__ P, float* __restrict__ S)
{
    __shared__ bf16 sdt[TT][TCH];
    __shared__ bf16 su[TT][TCH];
    __shared__ alignas(16) float sBC[TT][32];
    __shared__ int sflag;
    const int CH = LL / NCC;
    int bid = blockIdx.x;
    int cg = bid & 7;                 // DI/TCH = 8
    int c  = (bid >> 3) & (NCC - 1);
    int b  = (bid >> 3) / NCC;
    int d0 = cg * TCH;
    int tid = threadIdx.x;
    int w = tid >> 6, l = tid & 63;
    int lrow = l >> 5, lcol = (l & 31) * 8;
    int brow = l >> 3, bcol = (l & 7) * 4;
    int d = d0 + tid;

    if (tid == 0) sflag = 0;
    float Ads[16];
    #pragma unroll
    for (int q = 0; q < 4; q++) {
        float4 a4 = *(const float4*)&A_log[(size_t)d * DS + q * 4];
        Ads[q*4+0] = -__expf(a4.x); Ads[q*4+1] = -__expf(a4.y);
        Ads[q*4+2] = -__expf(a4.z); Ads[q*4+3] = -__expf(a4.w);
    }
    const float A0 = Ads[0];
    int bad = 0;
    #pragma unroll
    for (int s = 1; s < 16; s++) {
        float tgt = (float)(s + 1) * A0;
        bad |= (fabsf(Ads[s] - tgt) > 1e-5f * fabsf(tgt) + 1e-30f) ? 1 : 0;
    }
    __syncthreads();
    if (bad) atomicOr(&sflag, 1);
    __syncthreads();
    const int structured = (sflag == 0);

    const size_t rowbase = (size_t)b * LL + c * CH;
    float dsum = 0.f;

    if (structured) {
        f32x2 h2[8] = {};
        for (int t0 = 0; t0 < CH; t0 += TT) {
            #pragma unroll
            for (int pp = 0; pp < 2; pp++) {
                int r0 = (pp * 4 + w) * 2;
                size_t grow = rowbase + t0 + r0 + lrow;
                gld_lds16(dty + grow * DI + d0 + lcol, &sdt[r0][0]);
                gld_lds16(xc  + grow * DI + d0 + lcol, &su[r0][0]);
            }
            if (w < 2)
                gld_lds16(xdbl + (rowbase + t0 + w * 8 + brow) * 96 + DTR + bcol,
                          &sBC[w * 8][0]);
            __syncthreads();
            #pragma unroll
            for (int t = 0; t < TT; t++) {
                float dtv = b2f(sdt[t][tid]);
                float uv  = b2f(su[t][tid]);
                float tmp = dtv * uv;
                dsum += dtv;
                float4 B0 = ((const float4*)&sBC[t][0])[0];
                float4 B1 = ((const float4*)&sBC[t][0])[1];
                float4 B2 = ((const float4*)&sBC[t][0])[2];
                float4 B3 = ((const float4*)&sBC[t][0])[3];
                f32x2 bv2[8] = {{B0.x,B0.y},{B0.z,B0.w},{B1.x,B1.y},{B1.z,B1.w},
                                {B2.x,B2.y},{B2.z,B2.w},{B3.x,B3.y},{B3.z,B3.w}};
                f32x2 dA2[8];
                dA2_tree(__expf(dtv * A0), dA2);
                f32x2 tmp2 = {tmp, tmp};
                #pragma unroll
                for (int i = 0; i < 8; i++)
                    h2[i] = dA2[i] * h2[i] + tmp2 * bv2[i];
            }
            __syncthreads();
        }
        size_t o = ((size_t)(b * NCC + c) * DI + d) * DS;
        #pragma unroll
        for (int q = 0; q < 4; q++) {
            float4 pv = make_float4(__expf(Ads[q*4+0]*dsum), __expf(Ads[q*4+1]*dsum),
                                    __expf(Ads[q*4+2]*dsum), __expf(Ads[q*4+3]*dsum));
            *(float4*)&P[o + q*4] = pv;
            *(float4*)&S[o + q*4] = make_float4(h2[q*2].x, h2[q*2].y,
                                                h2[q*2+1].x, h2[q*2+1].y);
        }
    } else {
        float h[16];
        #pragma unroll
        for (int s = 0; s < 16; s++) h[s] = 0.f;
        for (int t0 = 0; t0 < CH; t0 += TT) {
            #pragma unroll
            for (int pp = 0; pp < 2; pp++) {
                int r0 = (pp * 4 + w) * 2;
                size_t grow = rowbase + t0 + r0 + lrow;
                gld_lds16(dty + grow * DI + d0 + lcol, &sdt[r0][0]);
                gld_lds16(xc  + grow * DI + d0 + lcol, &su[r0][0]);
            }
            if (w < 2)
                gld_lds16(xdbl + (rowbase + t0 + w * 8 + brow) * 96 + DTR + bcol,
                          &sBC[w * 8][0]);
            __syncthreads();
            for (int t = 0; t < TT; t++) {
                float dtv = b2f(sdt[t][tid]);
                float uv  = b2f(su[t][tid]);
                float tmp = dtv * uv;
                dsum += dtv;
                const float4* bc = (const float4*)&sBC[t][0];
                float4 B0 = bc[0], B1 = bc[1], B2 = bc[2], B3 = bc[3];
                float Bv[16] = {B0.x,B0.y,B0.z,B0.w, B1.x,B1.y,B1.z,B1.w,
                                B2.x,B2.y,B2.z,B2.w, B3.x,B3.y,B3.z,B3.w};
                #pragma unroll
                for (int s = 0; s < 16; s++) {
                    float dA = __expf(dtv * Ads[s]);
                    h[s] = dA * h[s] + tmp * Bv[s];
                }
            }
            __syncthreads();
        }
        size_t o = ((size_t)(b * NCC + c) * DI + d) * DS;
        #pragma unroll
        for (int q = 0; q < 4; q++) {
            float4 pv = make_float4(__expf(Ads[q*4+0]*dsum), __expf(Ads[q*4+1]*dsum),
                                    __expf(Ads[q*4+2]*dsum), __expf(Ads[q*4+3]*dsum));
            *(float4*)&P[o + q*4] = pv;
            *(float4*)&S[o + q*4] = make_float4(h[q*4], h[q*4+1], h[q*4+2], h[q*4+3]);
        }
    }
}

template<int NCC>
__global__ __launch_bounds__(256) void scan_combine(
    const float* __restrict__ P, float* __restrict__ S)
{
    int g = blockIdx.x * 256 + threadIdx.x;   // B*DI*DS threads
    int b = g >> 15;                          // DI*DS = 32768
    int rem = g & 32767;
    float h = 0.f;
    #pragma unroll
    for (int c = 0; c < NCC; c++) {
        size_t o = ((size_t)(b * NCC + c) << 15) + rem;
        float p = P[o], sv = S[o];
        S[o] = h;                             // h_in for chunk c
        h = p * h + sv;
    }
}

template<int NCC>
__global__ __launch_bounds__(256) void scan_part2(
    const float* __restrict__ xdbl, bf16* __restrict__ dty,
    const bf16* __restrict__ xc, const bf16* __restrict__ xz,
    const float* __restrict__ A_log, const float* __restrict__ Dp,
    const float* __restrict__ Hin)
{
    __shared__ bf16 sdt[TT][TCH];
    __shared__ bf16 su[TT][TCH];
    __shared__ bf16 sz[TT][TCH];
    __shared__ alignas(16) float sBC[TT][32];
    __shared__ int sflag;
    const int CH = LL / NCC;
    int bid = blockIdx.x;
    int cg = bid & 7;
    int c  = (bid >> 3) & (NCC - 1);
    int b  = (bid >> 3) / NCC;
    int d0 = cg * TCH;
    int tid = threadIdx.x;
    int w = tid >> 6, l = tid & 63;
    int lrow = l >> 5, lcol = (l & 31) * 8;
    int brow = l >> 3, bcol = (l & 7) * 4;
    int d = d0 + tid;

    if (tid == 0) sflag = 0;
    float Ads[16];
    #pragma unroll
    for (int q = 0; q < 4; q++) {
        float4 a4 = *(const float4*)&A_log[(size_t)d * DS + q * 4];
        Ads[q*4+0] = -__expf(a4.x); Ads[q*4+1] = -__expf(a4.y);
        Ads[q*4+2] = -__expf(a4.z); Ads[q*4+3] = -__expf(a4.w);
    }
    const float A0 = Ads[0];
    int bad = 0;
    #pragma unroll
    for (int s = 1; s < 16; s++) {
        float tgt = (float)(s + 1) * A0;
        bad |= (fabsf(Ads[s] - tgt) > 1e-5f * fabsf(tgt) + 1e-30f) ? 1 : 0;
    }
    __syncthreads();
    if (bad) atomicOr(&sflag, 1);
    __syncthreads();
    const int structured = (sflag == 0);

    float dpd = Dp[d];
    size_t ho = ((size_t)(b * NCC + c) * DI + d) * DS;
    const size_t rowbase = (size_t)b * LL + c * CH;

    if (structured) {
        f32x2 h2[8];
        #pragma unroll
        for (int q = 0; q < 4; q++) {
            float4 hv = *(const float4*)&Hin[ho + q*4];
            h2[q*2]   = (f32x2){hv.x, hv.y};
            h2[q*2+1] = (f32x2){hv.z, hv.w};
        }
        for (int t0 = 0; t0 < CH; t0 += TT) {
            #pragma unroll
            for (int pp = 0; pp < 2; pp++) {
                int r0 = (pp * 4 + w) * 2;
                size_t grow = rowbase + t0 + r0 + lrow;
                gld_lds16(dty + grow * DI + d0 + lcol, &sdt[r0][0]);
                gld_lds16(xc  + grow * DI + d0 + lcol, &su[r0][0]);
                gld_lds16(xz  + grow * (2 * DI) + DI + d0 + lcol, &sz[r0][0]);
            }
            if (w < 2)
                gld_lds16(xdbl + (rowbase + t0 + w * 8 + brow) * 96 + DTR + bcol,
                          &sBC[w * 8][0]);
            __syncthreads();
            #pragma unroll
            for (int t = 0; t < TT; t++) {
                float dtv = b2f(sdt[t][tid]);
                float uv  = b2f(su[t][tid]);
                float tmp = dtv * uv;
                const float4* bc = (const float4*)&sBC[t][0];
                float4 B0 = bc[0], B1 = bc[1], B2 = bc[2], B3 = bc[3];
                float4 C0 = bc[4], C1 = bc[5], C2 = bc[6], C3 = bc[7];
                f32x2 bv2[8] = {{B0.x,B0.y},{B0.z,B0.w},{B1.x,B1.y},{B1.z,B1.w},
                                {B2.x,B2.y},{B2.z,B2.w},{B3.x,B3.y},{B3.z,B3.w}};
                f32x2 cv2[8] = {{C0.x,C0.y},{C0.z,C0.w},{C1.x,C1.y},{C1.z,C1.w},
                                {C2.x,C2.y},{C2.z,C2.w},{C3.x,C3.y},{C3.z,C3.w}};
                f32x2 dA2[8];
                dA2_tree(__expf(dtv * A0), dA2);
                f32x2 tmp2 = {tmp, tmp};
                f32x2 y2 = {0.f, 0.f};
                #pragma unroll
                for (int i = 0; i < 8; i++) {
                    h2[i] = dA2[i] * h2[i] + tmp2 * bv2[i];
                    y2 = y2 + h2[i] * cv2[i];
                }
                float y = y2.x + y2.y;
                float zv = b2f(sz[t][tid]);
                float yo = (y + uv * dpd) * (zv / (1.f + __expf(-zv)));
                dty[(rowbase + t0 + t) * DI + d] = f2b(yo);
            }
            __syncthreads();
        }
    } else {
        float h[16];
        #pragma unroll
        for (int q = 0; q < 4; q++) {
            float4 hv = *(const float4*)&Hin[ho + q*4];
            h[q*4] = hv.x; h[q*4+1] = hv.y; h[q*4+2] = hv.z; h[q*4+3] = hv.w;
        }
        for (int t0 = 0; t0 < CH; t0 += TT) {
            #pragma unroll
            for (int pp = 0; pp < 2; pp++) {
                int r0 = (pp * 4 + w) * 2;
                size_t grow = rowbase + t0 + r0 + lrow;
                gld_lds16(dty + grow * DI + d0 + lcol, &sdt[r0][0]);
                gld_lds16(xc  + grow * DI + d0 + lcol, &su[r0][0]);
                gld_lds16(xz  + grow * (2 * DI) + DI + d0 + lcol, &sz[r0][0]);
            }
            if (w < 2)
                gld_lds16(xdbl + (rowbase + t0 + w * 8 + brow) * 96 + DTR + bcol,
                          &sBC[w * 8][0]);
            __syncthreads();
            for (int t = 0; t < TT; t++) {
                float dtv = b2f(sdt[t][tid]);
                float uv  = b2f(su[t][tid]);
                float tmp = dtv * uv;
                const float4* bc = (const float4*)&sBC[t][0];
                float4 B0 = bc[0], B1 = bc[1], B2 = bc[2], B3 = bc[3];
                float4 C0 = bc[4], C1 = bc[5], C2 = bc[6], C3 = bc[7];
                float Bv[16] = {B0.x,B0.y,B0.z,B0.w, B1.x,B1.y,B1.z,B1.w,
                                B2.x,B2.y,B2.z,B2.w, B3.x,B3.y,B3.z,B3.w};
                float Cv[16] = {C0.x,C0.y,C0.z,C0.w, C1.x,C1.y,C1.z,C1.w,
                                C2.x,C2.y,C2.z,C2.w, C3.x,C3.y,C3.z,C3.w};
                float y0 = 0.f, y1 = 0.f;
                #pragma unroll
                for (int s = 0; s < 16; s++) {
                    float dA = __expf(dtv * Ads[s]);
                    h[s] = dA * h[s] + tmp * Bv[s];
                    if (s & 1) y1 = fmaf(h[s], Cv[s], y1);
                    else       y0 = fmaf(h[s], Cv[s], y0);
                }
                float y = y0 + y1;
                float zv = b2f(sz[t][tid]);
                float yo = (y + uv * dpd) * (zv / (1.f + __expf(-zv)));
                dty[(rowbase + t0 + t) * DI + d] = f2b(yo);
            }
            __syncthreads();
        }
    }
}

// ---------------- Monolithic scan (fallback when ws is small) ----------------
__global__ __launch_bounds__(256) void scan_mono(
    const float* __restrict__ xdbl, bf16* __restrict__ dty,
    const bf16* __restrict__ xc, const bf16* __restrict__ xz,
    const float* __restrict__ A_log, const float* __restrict__ Dp)
{
    const int TC = 64;
    int b = blockIdx.x >> 7;
    int dblk = blockIdx.x & 127;
    int d0 = dblk * 16;
    int tid = threadIdx.x;
    int s = tid & 15;
    int dg = tid >> 4;
    int d = d0 + dg;
    float Ads = -__expf(A_log[(size_t)d * DS + s]);
    float h = 0.f;
    __shared__ float sdt[TC][16], su[TC][16], sB[TC][16], sC[TC][16], sy[TC][16];
    const size_t rowbase = (size_t)b * LL;
    int wi = tid >> 2;
    int wj = (tid & 3) * 4;
    float4 dpv = *(const float4*)(Dp + d0 + wj);
    for (int t0 = 0; t0 < LL; t0 += TC) {
        {
            size_t g = (rowbase + t0 + wi) * (size_t)DI + d0 + wj;
            *(float4*)&sdt[wi][wj] = ld4(dty + g);
            *(float4*)&su[wi][wj]  = ld4(xc + g);
        }
        #pragma unroll
        for (int r = 0; r < 4; r++) {
            int i = (tid >> 4) + r * 16;
            size_t g = (rowbase + t0 + i) * 96;
            sB[i][s] = xdbl[g + DTR + s];
            sC[i][s] = xdbl[g + DTR + DS + s];
        }
        __syncthreads();
        for (int i = 0; i < TC; i++) {
            float dtv = sdt[i][dg];
            float dA = __expf(dtv * Ads);
            h = dA * h + dtv * su[i][dg] * sB[i][s];
            float yp = h * sC[i][s];
            yp += __shfl_xor(yp, 1);
            yp += __shfl_xor(yp, 2);
            yp += __shfl_xor(yp, 4);
            yp += __shfl_xor(yp, 8);
            if (s == 0) sy[i][dg] = yp;
        }
        __syncthreads();
        {
            size_t g  = (rowbase + t0 + wi) * (size_t)DI + d0 + wj;
            size_t gz = (rowbase + t0 + wi) * (size_t)(2 * DI) + DI + d0 + wj;
            float4 zv = ld4(xz + gz);
            float4 yv = *(const float4*)&sy[wi][wj];
            float4 uv = *(const float4*)&su[wi][wj];
            ushort4 o;
            o.x = f2b((yv.x + uv.x * dpv.x) * (zv.x / (1.f + __expf(-zv.x))));
            o.y = f2b((yv.y + uv.y * dpv.y) * (zv.y / (1.f + __expf(-zv.y))));
            o.z = f2b((yv.z + uv.z * dpv.z) * (zv.z / (1.f + __expf(-zv.z))));
            o.w = f2b((yv.w + uv.w * dpv.w) * (zv.w / (1.f + __expf(-zv.w))));
            *(ushort4*)(dty + g) = o;
        }
        __syncthreads();
    }
}

// ---------------- slow conv (fallback path: f32 weights, 4 ch/thread) --------
__global__ __launch_bounds__(256) void conv_silu_slow(
    const bf16* __restrict__ xz, const float* __restrict__ cw,
    const float* __restrict__ cb, bf16* __restrict__ xc)
{
    int idx = blockIdx.x * 256 + threadIdx.x;
    int d4 = idx & (DI / 4 - 1);
    int bl = idx >> 9;
    int l = bl & (LL - 1);
    int d0 = d4 * 4;
    float4 bias = *(const float4*)(cb + d0);
    float acc[4] = {bias.x, bias.y, bias.z, bias.w};
    #pragma unroll
    for (int k = 0; k < 4; k++) {
        if (l - 3 + k < 0) continue;
        float4 xv = ld4(xz + (size_t)(bl - 3 + k) * (2 * DI) + d0);
        acc[0] = fmaf(xv.x, cw[(d0 + 0) * 4 + k], acc[0]);
        acc[1] = fmaf(xv.y, cw[(d0 + 1) * 4 + k], acc[1]);
        acc[2] = fmaf(xv.z, cw[(d0 + 2) * 4 + k], acc[2]);
        acc[3] = fmaf(xv.w, cw[(d0 + 3) * 4 + k], acc[3]);
    }
    ushort4 o;
    o.x = f2b(acc[0] / (1.f + __expf(-acc[0])));
    o.y = f2b(acc[1] / (1.f + __expf(-acc[1])));
    o.z = f2b(acc[2] / (1.f + __expf(-acc[2])));
    o.w = f2b(acc[3] / (1.f + __expf(-acc[3])));
    *(ushort4*)(xc + (size_t)bl * DI + d0) = o;
}

// ---------------------------------------------------------------------------
extern "C" void kernel_launch(void* const* d_in, const int* in_sizes, int n_in,
                              void* d_out, int out_size, void* d_ws, size_t ws_size,
                              hipStream_t stream)
{
    const float* x      = (const float*)d_in[0];
    const float* ln_w   = (const float*)d_in[1];
    const float* ln_b   = (const float*)d_in[2];
    const float* W_in   = (const float*)d_in[3];
    const float* conv_w = (const float*)d_in[4];
    const float* conv_b = (const float*)d_in[5];
    const float* W_x    = (const float*)d_in[6];
    const float* W_dt   = (const float*)d_in[7];
    const float* b_dt   = (const float*)d_in[8];
    const float* A_log  = (const float*)d_in[9];
    const float* Dp     = (const float*)d_in[10];
    const float* W_out  = (const float*)d_in[11];
    float* out = (float*)d_out;

    const size_t R = (size_t)BB * LL;   // 8192 rows

    // ws: xz bf16 | dty bf16 | xdbl f32 | P,S f32 (NCC-sized) | W_x_b | W_dt_b
    //     | dtr bf16 | cwt bf16 | [W_out_b2 bf16 if room]
    bf16*  xz    = (bf16*)d_ws;                    // R * 2*DI
    bf16*  dty   = xz + R * 2 * DI;                // R * DI
    float* xdbl  = (float*)(dty + R * DI);         // R * 96
    float* Pbuf  = xdbl + R * 96;

    const size_t headB = (size_t)((char*)Pbuf - (char*)d_ws);
    const size_t tailB = (size_t)(128 * DI + DI * DTR + R * DTR + 4 * DI) * 2 + 64;
    const size_t psU   = (size_t)BB * DI * DS * 4;   // per-chunk P/S bytes
    const int ncc = (ws_size >= headB + 2 * (32 * psU) + tailB) ? 32 : 16;
    const size_t psB = (size_t)ncc * psU;

    float* Sbuf   = (float*)((char*)Pbuf + psB);
    bf16*  W_x_b  = (bf16*)((char*)Sbuf + psB);    // 128*DI (96 used)
    bf16*  W_dt_b = W_x_b + 128 * DI;              // DI * DTR
    bf16*  dtr    = W_dt_b + DI * DTR;             // R * DTR
    bf16*  cwt    = dtr + R * DTR;                 // 4 * DI
    bf16*  W_out_b2 = cwt + 4 * DI;                // DM * DI (optional)
    const size_t ws_need = (size_t)((char*)(cwt + 4 * DI) - (char*)d_ws);
    const bool fast = ws_size >= ws_need;
    const size_t ws_need_w = (size_t)((char*)(W_out_b2 + (size_t)DM * DI) - (char*)d_ws);
    const int dowout = (fast && ws_size >= ws_need_w) ? 1 : 0;

    bf16*  W_in_b  = dty;   // dead before dt-gemm writes dty
    bf16*  W_out_b = xz;    // late-convert fallback (z dead after scan)

    bf16* xn = (bf16*)d_out;
    bf16* xc = (bf16*)d_out;

    // 0+1. fused prologue: LayerNorm + all weight converts (1 launch)
    {
        int nb = BB * LL + 4096;                    // LN + W_in
        if (fast) nb += 192 + 128 + 8 + (dowout ? 2048 : 0);
        prep_kernel<<<nb, 256, 0, stream>>>(
            x, ln_w, ln_b, xn, W_in, W_in_b, W_x, W_x_b, W_dt, W_dt_b,
            conv_w, cwt, W_out, W_out_b2, fast ? 1 : 0, dowout);
    }

    // 2. in_proj (8-phase 256^2 MFMA, WAR-interleave): xz = xn @ W_in^T
    for (int half = 0; half < 2; half++) {
        gemm_8p<0, bf16><<<dim3(16 * 16), 512, 0, stream>>>(
            xn + (size_t)half * 4096 * DM, DM, W_in_b, DM,
            xz + (size_t)half * 4096 * (2 * DI), 2 * DI, DM, nullptr, 16);
    }

    if (fast) {
        // 3. conv + SiLU -> xc (8 ch/thread, tap-major bf16 weights)
        conv_silu_kernel<<<(int)(R * DI / 8 / 256), 256, 0, stream>>>(
            xz, cwt, conv_b, xc);
        // 4a. x_proj MFMA -> xdbl f32 + dtr bf16
        xproj_mfma<<<(int)(R / 32), 256, 0, stream>>>(xc, W_x_b, xdbl, dtr);
        // 4b. dt = softplus(dtr @ W_dt^T + b_dt) -> dty bf16 (MFMA, K=64)
        gemm_mfma<1, bf16><<<dim3(DI / 128, R / 128), 256, 0, stream>>>(
            dtr, DTR, W_dt_b, DTR, dty, DI, DTR, b_dt);
        // 5. chunked scan (NCC chunks, TT=16 staged tiles)
        if (ncc == 32) {
            scan_part1<32><<<BB * 32 * (DI / TCH), 256, 0, stream>>>(
                xdbl, dty, xc, A_log, Pbuf, Sbuf);
            scan_combine<32><<<BB * DI * DS / 256, 256, 0, stream>>>(Pbuf, Sbuf);
            scan_part2<32><<<BB * 32 * (DI / TCH), 256, 0, stream>>>(
                xdbl, dty, xc, xz, A_log, Dp, Sbuf);
        } else {
            scan_part1<16><<<BB * 16 * (DI / TCH), 256, 0, stream>>>(
                xdbl, dty, xc, A_log, Pbuf, Sbuf);
            scan_combine<16><<<BB * DI * DS / 256, 256, 0, stream>>>(Pbuf, Sbuf);
            scan_part2<16><<<BB * 16 * (DI / TCH), 256, 0, stream>>>(
                xdbl, dty, xc, xz, A_log, Dp, Sbuf);
        }
    } else {
        // fallback: slow conv + f32 small GEMMs + monolithic scan
        conv_silu_slow<<<(int)(R * DI / 4 / 256), 256, 0, stream>>>(
            xz, conv_w, conv_b, xc);
        gemm_nt<0><<<dim3(2, R / 64), 256, 0, stream>>>(
            xc, DI, W_x, DI, xdbl, 96, (int)R, 96, DI, nullptr);
        gemm_nt<1><<<dim3(DI / 64, R / 64), 256, 0, stream>>>(
            xdbl, 96, W_dt, DTR, dty, DI, (int)R, DI, DTR, b_dt);
        scan_mono<<<BB * (DI / 16), 256, 0, stream>>>(
            xdbl, dty, xc, xz, A_log, Dp);
    }

    // 5b. late W_out convert only if no dedicated buffer (z dead after scan)
    const bf16* W_out_use = dowout ? (const bf16*)W_out_b2 : (const bf16*)W_out_b;
    if (!dowout)
        f2b_kernel<<<(DM * DI / 4) / 256, 256, 0, stream>>>(W_out, W_out_b, DM * DI / 4);

    // 6. out_proj (8-phase 256x128 MFMA, full-GPU grid, WAR-interleave)
    gemm_8p_n128<2, float><<<dim3((int)(R / 256) * (DM / 128)), 512, 0, stream>>>(
        dty, DI, W_out_use, DI, out, DM, DI, x, DM / 128);
}

// Round 12
// 374.819 us; speedup vs baseline: 1.1568x; 1.0396x over previous
//
#include <hip/hip_runtime.h>
#include <math.h>

#define BB 4
#define LL 2048
#define DM 1024
#define DI 2048
#define DS 16
#define DTR 64
#define TCH 256          // channels per scan block
#define TT 16            // timesteps per staged tile

typedef unsigned short bf16;
typedef __attribute__((ext_vector_type(8))) short bf16x8;
typedef __attribute__((ext_vector_type(4))) float f32x4;
typedef __attribute__((ext_vector_type(2))) float f32x2;

__device__ inline float b2f(bf16 u) { return __uint_as_float(((unsigned)u) << 16); }
__device__ inline bf16 f2b(float f) {
    unsigned u = __float_as_uint(f);
    u += 0x7FFF + ((u >> 16) & 1);   // round-to-nearest-even
    return (bf16)(u >> 16);
}

__device__ inline float4 ld4(const float* p) { return *(const float4*)p; }
__device__ inline float4 ld4(const bf16* p) {
    ushort4 v = *(const ushort4*)p;
    return make_float4(b2f(v.x), b2f(v.y), b2f(v.z), b2f(v.w));
}
__device__ inline void st1(float* p, float v) { *p = v; }
__device__ inline void st1(bf16* p, float v) { *p = f2b(v); }

// cheap softplus: hw v_exp_f32/v_log_f32 (~8 VALU instrs); bf16-sufficient.
__device__ inline float softplus_fast(float v) {
    return (v > 15.f) ? v : __logf(1.f + __expf(v));
}

// async global->LDS, 16 bytes per lane; LDS dest = wave-uniform base + lane*16
__device__ inline void gld_lds16(const void* g, void* l) {
    __builtin_amdgcn_global_load_lds(
        (const __attribute__((address_space(1))) unsigned int*)g,
        (__attribute__((address_space(3))) unsigned int*)l, 16, 0, 0);
}

// dA2[i] = {c1^(2i+1), c1^(2i+2)}: 3 scalar + 7 packed muls, shallow deps.
// clang emits v_pk_mul_f32 for <2 x float> products on gfx950.
__device__ inline void dA2_tree(float c1, f32x2* dA2) {
    float c2 = c1 * c1;
    float c4 = c2 * c2;
    float c8 = c4 * c4;
    f32x2 c2v = {c2, c2};
    f32x2 c8v = {c8, c8};
    dA2[0] = (f32x2){c1, c2};
    dA2[1] = dA2[0] * c2v;     // c3,c4
    dA2[2] = dA2[1] * c2v;     // c5,c6
    dA2[3] = dA2[2] * c2v;     // c7,c8
    dA2[4] = dA2[0] * c8v;
    dA2[5] = dA2[1] * c8v;
    dA2[6] = dA2[2] * c8v;
    dA2[7] = dA2[3] * c8v;
}

// ---------------- f32 -> bf16 convert (late W_out fallback only) -------------
__global__ __launch_bounds__(256) void f2b_kernel(const float* __restrict__ in,
    bf16* __restrict__ out, int n4)
{
    int i = blockIdx.x * 256 + threadIdx.x;
    if (i >= n4) return;
    float4 v = *(const float4*)(in + (size_t)i * 4);
    ushort4 o = { f2b(v.x), f2b(v.y), f2b(v.z), f2b(v.w) };
    *(ushort4*)(out + (size_t)i * 4) = o;
}

// ---------------- Fused prologue: LayerNorm + all weight converts ------------
__global__ __launch_bounds__(256) void prep_kernel(
    const float* __restrict__ x, const float* __restrict__ lw,
    const float* __restrict__ lb, bf16* __restrict__ xn,
    const float* __restrict__ W_in, bf16* __restrict__ W_in_b,
    const float* __restrict__ W_x, bf16* __restrict__ W_x_b,
    const float* __restrict__ W_dt, bf16* __restrict__ W_dt_b,
    const float* __restrict__ cw, bf16* __restrict__ cwt,
    const float* __restrict__ W_out, bf16* __restrict__ W_out_b,
    int dofast, int dowout)
{
    int blk = blockIdx.x;
    int tid = threadIdx.x;
    if (blk < BB * LL) {                       // ---- LayerNorm row ----
        int row = blk;
        const float* xr = x + (size_t)row * DM;
        float4 v = *(const float4*)(xr + tid * 4);
        float s1 = v.x + v.y + v.z + v.w;
        float s2 = v.x * v.x + v.y * v.y + v.z * v.z + v.w * v.w;
        #pragma unroll
        for (int o = 32; o > 0; o >>= 1) {
            s1 += __shfl_xor(s1, o);
            s2 += __shfl_xor(s2, o);
        }
        __shared__ float r1[4], r2[4];
        __shared__ float smu, srs;
        int wv = tid >> 6;
        if ((tid & 63) == 0) { r1[wv] = s1; r2[wv] = s2; }
        __syncthreads();
        if (tid == 0) {
            float t1 = r1[0] + r1[1] + r1[2] + r1[3];
            float t2 = r2[0] + r2[1] + r2[2] + r2[3];
            float mu = t1 * (1.0f / DM);
            float var = t2 * (1.0f / DM) - mu * mu;
            smu = mu;
            srs = rsqrtf(var + 1e-5f);
        }
        __syncthreads();
        float mu = smu, rs = srs;
        float4 wv4 = *(const float4*)(lw + tid * 4);
        float4 bv4 = *(const float4*)(lb + tid * 4);
        ushort4 o;
        o.x = f2b((v.x - mu) * rs * wv4.x + bv4.x);
        o.y = f2b((v.y - mu) * rs * wv4.y + bv4.y);
        o.z = f2b((v.z - mu) * rs * wv4.z + bv4.z);
        o.w = f2b((v.w - mu) * rs * wv4.w + bv4.w);
        *(ushort4*)(xn + (size_t)row * DM + tid * 4) = o;
        return;
    }
    blk -= BB * LL;
    if (blk < 4096) {                          // ---- W_in f2b ----
        int i = blk * 256 + tid;
        float4 v = *(const float4*)(W_in + (size_t)i * 4);
        ushort4 o = { f2b(v.x), f2b(v.y), f2b(v.z), f2b(v.w) };
        *(ushort4*)(W_in_b + (size_t)i * 4) = o;
        return;
    }
    blk -= 4096;
    if (!dofast) return;
    if (blk < 192) {                           // ---- W_x f2b ----
        int i = blk * 256 + tid;
        float4 v = *(const float4*)(W_x + (size_t)i * 4);
        ushort4 o = { f2b(v.x), f2b(v.y), f2b(v.z), f2b(v.w) };
        *(ushort4*)(W_x_b + (size_t)i * 4) = o;
        return;
    }
    blk -= 192;
    if (blk < 128) {                           // ---- W_dt f2b ----
        int i = blk * 256 + tid;
        float4 v = *(const float4*)(W_dt + (size_t)i * 4);
        ushort4 o = { f2b(v.x), f2b(v.y), f2b(v.z), f2b(v.w) };
        *(ushort4*)(W_dt_b + (size_t)i * 4) = o;
        return;
    }
    blk -= 128;
    if (blk < 8) {                             // ---- conv weight transpose ----
        int d = blk * 256 + tid;
        float4 w = *(const float4*)(cw + d * 4);
        cwt[0 * DI + d] = f2b(w.x);
        cwt[1 * DI + d] = f2b(w.y);
        cwt[2 * DI + d] = f2b(w.z);
        cwt[3 * DI + d] = f2b(w.w);
        return;
    }
    blk -= 8;
    if (dowout && blk < 2048) {                // ---- W_out f2b ----
        int i = blk * 256 + tid;
        float4 v = *(const float4*)(W_out + (size_t)i * 4);
        ushort4 o = { f2b(v.x), f2b(v.y), f2b(v.z), f2b(v.w) };
        *(ushort4*)(W_out_b + (size_t)i * 4) = o;
    }
}

// ============================================================================
// 256x256 8-phase MFMA GEMM (NT), WAR-interleaved fragment prefetch.
// ============================================================================
#define BARR  do { asm volatile("" ::: "memory"); __builtin_amdgcn_s_barrier(); \
                   asm volatile("" ::: "memory"); } while (0)
#define LGKM0 do { asm volatile("s_waitcnt lgkmcnt(0)" ::: "memory"); \
                   __builtin_amdgcn_sched_barrier(0); } while (0)
#define VMC4  asm volatile("s_waitcnt vmcnt(4)" ::: "memory")
#define VMC2  asm volatile("s_waitcnt vmcnt(2)" ::: "memory")
#define SCHED0 __builtin_amdgcn_sched_barrier(0)

template<int EPI, typename TC>
__global__ __launch_bounds__(512, 2) void gemm_8p(
    const bf16* __restrict__ A, int lda,
    const bf16* __restrict__ B, int ldb,
    TC* __restrict__ C, int ldc,
    int K, const float* __restrict__ aux, int nbn)
{
    __shared__ bf16 lds[65536];          // 128 KB: A [0,64K) B [64K,128K)
    char* L = (char*)lds;
    const int tid = threadIdx.x;
    const int lane = tid & 63;
    const int w = tid >> 6;              // 0..7
    const int wm = w >> 2;               // 0..1
    const int wn = w & 3;                // 0..3

    int nwg = gridDim.x;
    int bid = blockIdx.x;
    int sb = bid;
    if ((nwg & 7) == 0) sb = (bid & 7) * (nwg >> 3) + (bid >> 3);
    const int m0 = (sb / nbn) * 256;
    const int n0 = (sb % nbn) * 256;

    const size_t lda2 = (size_t)lda * 2;
    const size_t ldb2 = (size_t)ldb * 2;
    const int l8 = lane >> 3;
    const int scol = ((lane & 7) ^ l8) << 4;
    const size_t offA = (size_t)(w * 8 + l8) * lda2 + scol;
    const size_t offB = (size_t)(w * 8 + l8) * ldb2 + scol;
    const char* Ab = (const char*)A + (size_t)m0 * lda2;
    const char* Bb = (const char*)B + (size_t)n0 * ldb2;

    const int fm = lane & 15, fq = lane >> 4;
    const int prow = fm * 128;
    const int px0 = (fq << 4) ^ ((fm & 7) << 4);
    const int px1 = (64 | (fq << 4)) ^ ((fm & 7) << 4);
    const char* Lar = L + wm * 16384 + prow;
    const char* Lbr = L + 65536 + (wn >> 1) * 16384 + (wn & 1) * 8192 + prow;

    f32x4 acc[8][4] = {};
    bf16x8 a_[2][2], b_[4][2];

#define ST_A(sbuf, hh, t) do { \
    const char* s_ = Ab + (size_t)(hh) * 128 * lda2 + (size_t)(t) * 128 + offA; \
    gld_lds16(s_,             L + (sbuf) * 32768 + (hh) * 16384 + w * 1024); \
    gld_lds16(s_ + 64 * lda2, L + (sbuf) * 32768 + (hh) * 16384 + 8192 + w * 1024); \
  } while (0)
#define ST_B(sbuf, hh, t) do { \
    const char* s_ = Bb + (size_t)(hh) * 128 * ldb2 + (size_t)(t) * 128 + offB; \
    gld_lds16(s_,             L + 65536 + (sbuf) * 32768 + (hh) * 16384 + w * 1024); \
    gld_lds16(s_ + 64 * ldb2, L + 65536 + (sbuf) * 32768 + (hh) * 16384 + 8192 + w * 1024); \
  } while (0)
#define DS_A1(rb, q, kh) do { \
    a_[0][kh] = *(const bf16x8*)(Lar + (rb) * 32768 + ((q) * 32 +  0) * 128 + ((kh) ? px1 : px0)); \
    a_[1][kh] = *(const bf16x8*)(Lar + (rb) * 32768 + ((q) * 32 + 16) * 128 + ((kh) ? px1 : px0)); \
  } while (0)
#define DS_Bh(rb, kh) do { \
    _Pragma("unroll") \
    for (int ni = 0; ni < 4; ni++) \
      b_[ni][kh] = *(const bf16x8*)(Lbr + (rb) * 32768 + ni * 2048 + ((kh) ? px1 : px0)); \
  } while (0)
#define MFMA_H(q, kh) do { \
    _Pragma("unroll") \
    for (int mi = 0; mi < 2; mi++) \
      _Pragma("unroll") \
      for (int ni = 0; ni < 4; ni++) \
        acc[(q)*2+mi][ni] = __builtin_amdgcn_mfma_f32_16x16x32_bf16( \
            a_[mi][kh], b_[ni][kh], acc[(q)*2+mi][ni], 0, 0, 0); \
  } while (0)
#define PHASE(rb, q, rb2, q2, STAGE, DOVMC) do { \
    STAGE; \
    if (DOVMC) VMC4; \
    BARR; LGKM0; \
    __builtin_amdgcn_s_setprio(1); \
    MFMA_H(q, 0); \
    __builtin_amdgcn_s_setprio(0); \
    DS_A1(rb2, q2, 0); \
    if ((q) == 3) DS_Bh(rb2, 0); \
    SCHED0; \
    __builtin_amdgcn_s_setprio(1); \
    MFMA_H(q, 1); \
    __builtin_amdgcn_s_setprio(0); \
    DS_A1(rb2, q2, 1); \
    if ((q) == 3) DS_Bh(rb2, 1); \
    BARR; \
  } while (0)

    const int NT = K >> 6;               // K-tiles of 64 (NT even, >=2)
    ST_B(0, 0, 0); ST_B(0, 1, 0);
    ST_A(0, 0, 0); ST_A(0, 1, 0);
    ST_B(1, 0, 1); ST_B(1, 1, 1);
    VMC4;
    BARR;
    DS_Bh(0, 0); DS_Bh(0, 1);
    DS_A1(0, 0, 0); DS_A1(0, 0, 1);

    for (int t0 = 0; t0 < NT; t0 += 2) {
        const int tA1 = t0 + 1;
        const int tN2 = (t0 + 2 < NT) ? t0 + 2 : NT - 1;   // clamp: dead slot
        const int tN3 = (t0 + 3 < NT) ? t0 + 3 : NT - 1;
        // ---- K-tile t0 from buf0 ----
        PHASE(0, 0, 0, 1, ST_A(1, 0, tA1), 0);
        PHASE(0, 1, 0, 2, ST_A(1, 1, tA1), 0);
        PHASE(0, 2, 0, 3, ST_B(0, 0, tN2), 0);
        PHASE(0, 3, 1, 0, ST_B(0, 1, tN2), 1);
        // ---- K-tile t0+1 from buf1 ----
        PHASE(1, 0, 1, 1, ST_A(0, 0, tN2), 0);
        PHASE(1, 1, 1, 2, ST_A(0, 1, tN2), 0);
        PHASE(1, 2, 1, 3, ST_B(1, 0, tN3), 0);
        PHASE(1, 3, 0, 0, ST_B(1, 1, tN3), 1);
    }
    asm volatile("s_waitcnt vmcnt(0)" ::: "memory");  // drain DMA before exit

    #pragma unroll
    for (int i = 0; i < 8; i++) {
        #pragma unroll
        for (int ni = 0; ni < 4; ni++) {
            int n = n0 + wn * 64 + ni * 16 + fm;
            #pragma unroll
            for (int r = 0; r < 4; r++) {
                int m = m0 + wm * 128 + i * 16 + fq * 4 + r;
                float v = acc[i][ni][r];
                if (EPI == 2) v += aux[(size_t)m * ldc + n];
                st1(&C[(size_t)m * ldc + n], v);
            }
        }
    }
#undef ST_A
#undef ST_B
#undef DS_A1
#undef DS_Bh
#undef MFMA_H
#undef PHASE
}

// ============================================================================
// 256x128 variant (full-GPU grids for narrow N), same WAR-interleave.
// ============================================================================
template<int EPI, typename TC>
__global__ __launch_bounds__(512, 2) void gemm_8p_n128(
    const bf16* __restrict__ A, int lda,
    const bf16* __restrict__ B, int ldb,
    TC* __restrict__ C, int ldc,
    int K, const float* __restrict__ aux, int nbn)
{
    __shared__ bf16 lds[49152];          // 96 KB
    char* L = (char*)lds;
    const int tid = threadIdx.x;
    const int lane = tid & 63;
    const int w = tid >> 6;              // 0..7
    const int wm = w >> 1;               // 0..3
    const int wn = w & 1;                // 0..1

    int nwg = gridDim.x;
    int bid = blockIdx.x;
    int sb = bid;
    if ((nwg & 7) == 0) sb = (bid & 7) * (nwg >> 3) + (bid >> 3);
    const int m0 = (sb / nbn) * 256;
    const int n0 = (sb % nbn) * 128;

    const size_t lda2 = (size_t)lda * 2;
    const size_t ldb2 = (size_t)ldb * 2;
    const int l8 = lane >> 3;
    const int scol = ((lane & 7) ^ l8) << 4;
    const size_t offA = (size_t)(w * 8 + l8) * lda2 + scol;
    const size_t offB = (size_t)(w * 8 + l8) * ldb2 + scol;
    const char* Ab = (const char*)A + (size_t)m0 * lda2;
    const char* Bb = (const char*)B + (size_t)n0 * ldb2;

    const int fm = lane & 15, fq = lane >> 4;
    const int prow = fm * 128;
    const int px0 = (fq << 4) ^ ((fm & 7) << 4);
    const int px1 = (64 | (fq << 4)) ^ ((fm & 7) << 4);
    const char* Lar = L + wm * 8192 + prow;            // wm*64 rows * 128B
    const char* Lbr = L + 65536 + wn * 8192 + prow;    // wn*64 rows * 128B

    f32x4 acc[4][4] = {};
    bf16x8 a_[2], b_[4][2];

#define ST_A(sbuf, hh, t) do { \
    const char* s_ = Ab + (size_t)(hh) * 128 * lda2 + (size_t)(t) * 128 + offA; \
    gld_lds16(s_,             L + (sbuf) * 32768 + (hh) * 16384 + w * 1024); \
    gld_lds16(s_ + 64 * lda2, L + (sbuf) * 32768 + (hh) * 16384 + 8192 + w * 1024); \
  } while (0)
#define ST_B1(sbuf, hh, t) do { \
    const char* s_ = Bb + (size_t)(hh) * 64 * ldb2 + (size_t)(t) * 128 + offB; \
    gld_lds16(s_, L + 65536 + (sbuf) * 16384 + (hh) * 8192 + w * 1024); \
  } while (0)
#define DS_A1h(rb, q, kh) do { \
    a_[kh] = *(const bf16x8*)(Lar + (rb) * 32768 + ((q) * 16) * 128 + ((kh) ? px1 : px0)); \
  } while (0)
#define DS_Bh(rb, kh) do { \
    _Pragma("unroll") \
    for (int ni = 0; ni < 4; ni++) \
      b_[ni][kh] = *(const bf16x8*)(Lbr + (rb) * 16384 + ni * 2048 + ((kh) ? px1 : px0)); \
  } while (0)
#define MFMA_Hh(q, kh) do { \
    _Pragma("unroll") \
    for (int ni = 0; ni < 4; ni++) \
      acc[q][ni] = __builtin_amdgcn_mfma_f32_16x16x32_bf16( \
          a_[kh], b_[ni][kh], acc[q][ni], 0, 0, 0); \
  } while (0)
#define PHASE(rb, q, rb2, q2, STAGE, DOVMC) do { \
    STAGE; \
    if (DOVMC) VMC2; \
    BARR; LGKM0; \
    __builtin_amdgcn_s_setprio(1); \
    MFMA_Hh(q, 0); \
    __builtin_amdgcn_s_setprio(0); \
    DS_A1h(rb2, q2, 0); \
    if ((q) == 3) DS_Bh(rb2, 0); \
    SCHED0; \
    __builtin_amdgcn_s_setprio(1); \
    MFMA_Hh(q, 1); \
    __builtin_amdgcn_s_setprio(0); \
    DS_A1h(rb2, q2, 1); \
    if ((q) == 3) DS_Bh(rb2, 1); \
    BARR; \
  } while (0)

    const int NT = K >> 6;               // K-tiles of 64 (NT even, >=2)
    ST_B1(0, 0, 0); ST_B1(0, 1, 0);
    ST_A(0, 0, 0); ST_A(0, 1, 0);
    ST_B1(1, 0, 1); ST_B1(1, 1, 1);
    VMC2;
    BARR;
    DS_Bh(0, 0); DS_Bh(0, 1);
    DS_A1h(0, 0, 0); DS_A1h(0, 0, 1);

    for (int t0 = 0; t0 < NT; t0 += 2) {
        const int tA1 = t0 + 1;
        const int tN2 = (t0 + 2 < NT) ? t0 + 2 : NT - 1;   // clamp: dead slot
        const int tN3 = (t0 + 3 < NT) ? t0 + 3 : NT - 1;
        // ---- K-tile t0 from buf0 ----
        PHASE(0, 0, 0, 1, ST_A(1, 0, tA1), 0);
        PHASE(0, 1, 0, 2, ST_A(1, 1, tA1), 0);
        PHASE(0, 2, 0, 3, ST_B1(0, 0, tN2), 0);
        PHASE(0, 3, 1, 0, ST_B1(0, 1, tN2), 1);
        // ---- K-tile t0+1 from buf1 ----
        PHASE(1, 0, 1, 1, ST_A(0, 0, tN2), 0);
        PHASE(1, 1, 1, 2, ST_A(0, 1, tN2), 0);
        PHASE(1, 2, 1, 3, ST_B1(1, 0, tN3), 0);
        PHASE(1, 3, 0, 0, ST_B1(1, 1, tN3), 1);
    }
    asm volatile("s_waitcnt vmcnt(0)" ::: "memory");

    #pragma unroll
    for (int i = 0; i < 4; i++) {
        #pragma unroll
        for (int ni = 0; ni < 4; ni++) {
            int n = n0 + wn * 64 + ni * 16 + fm;
            #pragma unroll
            for (int r = 0; r < 4; r++) {
                int m = m0 + wm * 64 + i * 16 + fq * 4 + r;
                float v = acc[i][ni][r];
                if (EPI == 2) v += aux[(size_t)m * ldc + n];
                st1(&C[(size_t)m * ldc + n], v);
            }
        }
    }
#undef ST_A
#undef ST_B1
#undef DS_A1h
#undef DS_Bh
#undef MFMA_Hh
#undef PHASE
}

// ---------------- MFMA bf16 GEMM, NT (128x128, used for dt-GEMM K=64) --------
template<int EPI, typename TC>
__global__ __launch_bounds__(256) void gemm_mfma(
    const bf16* __restrict__ A, int lda,
    const bf16* __restrict__ B, int ldb,
    TC* __restrict__ C, int ldc,
    int K, const float* __restrict__ aux)
{
    __shared__ bf16 As[128 * 32];
    __shared__ bf16 Bs[128 * 32];
    const int tid = threadIdx.x;
    const int lane = tid & 63;
    const int w = tid >> 6;
    const int wm = w >> 1, wn = w & 1;
    const int m0 = blockIdx.y * 128, n0 = blockIdx.x * 128;

    const int srow = lane >> 2;
    const int schunk = (lane & 3) * 8;

    const int fm = lane & 15;
    const int fq = lane >> 4;

    f32x4 acc[4][4] = {};

    for (int kt = 0; kt < K; kt += 32) {
        #pragma unroll
        for (int i = 0; i < 2; i++) {
            int r0 = i * 64 + w * 16;
            gld_lds16(A + (size_t)(m0 + r0 + srow) * lda + kt + schunk, &As[r0 * 32]);
            gld_lds16(B + (size_t)(n0 + r0 + srow) * ldb + kt + schunk, &Bs[r0 * 32]);
        }
        __syncthreads();
        bf16x8 af[4], bfr[4];
        #pragma unroll
        for (int i = 0; i < 4; i++) {
            af[i]  = *(const bf16x8*)&As[(wm * 64 + i * 16 + fm) * 32 + fq * 8];
            bfr[i] = *(const bf16x8*)&Bs[(wn * 64 + i * 16 + fm) * 32 + fq * 8];
        }
        #pragma unroll
        for (int i = 0; i < 4; i++)
            #pragma unroll
            for (int j = 0; j < 4; j++)
                acc[i][j] = __builtin_amdgcn_mfma_f32_16x16x32_bf16(
                    af[i], bfr[j], acc[i][j], 0, 0, 0);
        __syncthreads();
    }

    #pragma unroll
    for (int i = 0; i < 4; i++) {
        #pragma unroll
        for (int r = 0; r < 4; r++) {
            int m = m0 + wm * 64 + i * 16 + fq * 4 + r;
            #pragma unroll
            for (int j = 0; j < 4; j++) {
                int n = n0 + wn * 64 + j * 16 + fm;
                float v = acc[i][j][r];
                if (EPI == 1) {
                    v = softplus_fast(v + aux[n]);
                } else if (EPI == 2) {
                    v += aux[(size_t)m * ldc + n];
                }
                st1(&C[(size_t)m * ldc + n], v);
            }
        }
    }
}

// ---------------- x_proj MFMA: xdbl[R,96] = xc[R,DI] @ W_x[96,DI]^T ----------
__global__ __launch_bounds__(256) void xproj_mfma(
    const bf16* __restrict__ A,      // xc [R, DI]
    const bf16* __restrict__ Bm,     // W_x bf16, padded to 128 rows [128, DI]
    float* __restrict__ Cx,          // xdbl [R, 96]
    bf16* __restrict__ dtr)          // [R, 64]
{
    __shared__ bf16 As[32 * 32];
    __shared__ bf16 Bs[128 * 32];
    const int tid = threadIdx.x;
    const int lane = tid & 63;
    const int w = tid >> 6;
    const int wm = w >> 1, wn = w & 1;
    const int m0 = blockIdx.x * 32;
    const int srow = lane >> 2;
    const int schunk = (lane & 3) * 8;
    const int fm = lane & 15;
    const int fq = lane >> 4;
    f32x4 acc[3] = {};
    for (int kt = 0; kt < DI; kt += 32) {
        if (w < 2) {
            int r0 = w * 16;
            gld_lds16(A + (size_t)(m0 + r0 + srow) * DI + kt + schunk, &As[r0 * 32]);
        }
        {
            int r0 = w * 32;
            gld_lds16(Bm + (size_t)(r0 + srow) * DI + kt + schunk, &Bs[r0 * 32]);
            gld_lds16(Bm + (size_t)(r0 + 16 + srow) * DI + kt + schunk, &Bs[(r0 + 16) * 32]);
        }
        __syncthreads();
        bf16x8 af = *(const bf16x8*)&As[(wm * 16 + fm) * 32 + fq * 8];
        #pragma unroll
        for (int j = 0; j < 3; j++) {
            bf16x8 bf = *(const bf16x8*)&Bs[((wn * 3 + j) * 16 + fm) * 32 + fq * 8];
            acc[j] = __builtin_amdgcn_mfma_f32_16x16x32_bf16(af, bf, acc[j], 0, 0, 0);
        }
        __syncthreads();
    }
    #pragma unroll
    for (int j = 0; j < 3; j++) {
        int col = (wn * 3 + j) * 16 + fm;
        #pragma unroll
        for (int r = 0; r < 4; r++) {
            int m = m0 + wm * 16 + fq * 4 + r;
            float v = acc[j][r];
            Cx[(size_t)m * 96 + col] = v;
            if (col < 64) dtr[(size_t)m * 64 + col] = f2b(v);
        }
    }
}

// ---------------- Tiled f32-compute GEMM (fallback path only) ----------------
template<int EPI, typename TA, typename TB, typename TC>
__global__ __launch_bounds__(256) void gemm_nt(
    const TA* __restrict__ A, int lda,
    const TB* __restrict__ B, int ldb,
    TC* __restrict__ C, int ldc,
    int M, int N, int K,
    const float* __restrict__ aux)
{
    __shared__ float As[16][64];
    __shared__ float Bs[16][64];
    int tid = threadIdx.x;
    int m0 = blockIdx.y * 64, n0 = blockIdx.x * 64;
    int lr = tid >> 2;
    int lc = (tid & 3) * 4;
    int tm = tid >> 4;
    int tn = tid & 15;
    float acc[4][4] = {};
    for (int kt = 0; kt < K; kt += 16) {
        float4 av = ld4(A + (size_t)(m0 + lr) * lda + kt + lc);
        float4 bv = make_float4(0.f, 0.f, 0.f, 0.f);
        if (n0 + lr < N)
            bv = ld4(B + (size_t)(n0 + lr) * ldb + kt + lc);
        As[lc + 0][lr] = av.x; As[lc + 1][lr] = av.y;
        As[lc + 2][lr] = av.z; As[lc + 3][lr] = av.w;
        Bs[lc + 0][lr] = bv.x; Bs[lc + 1][lr] = bv.y;
        Bs[lc + 2][lr] = bv.z; Bs[lc + 3][lr] = bv.w;
        __syncthreads();
        #pragma unroll
        for (int k = 0; k < 16; k++) {
            float4 a4 = *(const float4*)&As[k][tm * 4];
            float4 b4 = *(const float4*)&Bs[k][tn * 4];
            float am[4] = {a4.x, a4.y, a4.z, a4.w};
            float bn[4] = {b4.x, b4.y, b4.z, b4.w};
            #pragma unroll
            for (int i = 0; i < 4; i++)
                #pragma unroll
                for (int j = 0; j < 4; j++)
                    acc[i][j] = fmaf(am[i], bn[j], acc[i][j]);
        }
        __syncthreads();
    }
    #pragma unroll
    for (int i = 0; i < 4; i++) {
        int m = m0 + tm * 4 + i;
        #pragma unroll
        for (int j = 0; j < 4; j++) {
            int n = n0 + tn * 4 + j;
            if (n >= N) continue;
            float v = acc[i][j];
            if (EPI == 1) {
                v = softplus_fast(v + aux[n]);
            }
            st1(&C[(size_t)m * ldc + n], v);
        }
    }
}

// ---------------- Depthwise causal conv (4 taps) + SiLU ----------------------
__global__ __launch_bounds__(256) void conv_silu_kernel(
    const bf16* __restrict__ xz, const bf16* __restrict__ cwt,
    const float* __restrict__ cb, bf16* __restrict__ xc)
{
    int idx = blockIdx.x * 256 + threadIdx.x;   // R*DI/8 threads
    int d8 = idx & (DI / 8 - 1);                // 0..255
    int bl = idx >> 8;                          // 0..8191
    int l = bl & (LL - 1);
    int d0 = d8 * 8;
    float4 b0 = *(const float4*)(cb + d0);
    float4 b1 = *(const float4*)(cb + d0 + 4);
    float acc[8] = {b0.x, b0.y, b0.z, b0.w, b1.x, b1.y, b1.z, b1.w};
    #pragma unroll
    for (int k = 0; k < 4; k++) {
        if (l - 3 + k < 0) continue;
        bf16x8 xv = *(const bf16x8*)(xz + (size_t)(bl - 3 + k) * (2 * DI) + d0);
        bf16x8 wv = *(const bf16x8*)(cwt + k * DI + d0);
        #pragma unroll
        for (int j = 0; j < 8; j++)
            acc[j] = fmaf(b2f((bf16)xv[j]), b2f((bf16)wv[j]), acc[j]);
    }
    bf16x8 o;
    #pragma unroll
    for (int j = 0; j < 8; j++)
        o[j] = (short)f2b(acc[j] / (1.f + __expf(-acc[j])));
    *(bf16x8*)(xc + (size_t)bl * DI + d0) = o;
}

// ---------------- Chunked selective scan, thread-per-channel -----------------
// R7 memory layout + R11 packed math. P is stored as ONE scalar per (b,c,d):
// dsum = sum_t dt, since P[s] = exp(Ads[s]*dsum) exactly (any Ads). This
// shrinks P 16x so NCC=32 (1024 blocks, 4/CU) fits the workspace.
template<int NCC>
__global__ __launch_bounds__(256) void scan_part1(
    const float* __restrict__ xdbl, const bf16* __restrict__ dty,
    const bf16* __restrict__ xc, const float* __restrict__ A_log,
    float* __restrict__ Pd, float* __restrict__ S)
{
    __shared__ bf16 sdt[TT][TCH];
    __shared__ bf16 su[TT][TCH];
    __shared__ alignas(16) float sBC[TT][32];
    __shared__ int sflag;
    const int CH = LL / NCC;
    int bid = blockIdx.x;
    int cg = bid & 7;                 // DI/TCH = 8
    int c  = (bid >> 3) & (NCC - 1);
    int b  = (bid >> 3) / NCC;
    int d0 = cg * TCH;
    int tid = threadIdx.x;
    int w = tid >> 6, l = tid & 63;
    int lrow = l >> 5, lcol = (l & 31) * 8;
    int brow = l >> 3, bcol = (l & 7) * 4;
    int d = d0 + tid;

    if (tid == 0) sflag = 0;
    float Ads[16];
    #pragma unroll
    for (int q = 0; q < 4; q++) {
        float4 a4 = *(const float4*)&A_log[(size_t)d * DS + q * 4];
        Ads[q*4+0] = -__expf(a4.x); Ads[q*4+1] = -__expf(a4.y);
        Ads[q*4+2] = -__expf(a4.z); Ads[q*4+3] = -__expf(a4.w);
    }
    const float A0 = Ads[0];
    int bad = 0;
    #pragma unroll
    for (int s = 1; s < 16; s++) {
        float tgt = (float)(s + 1) * A0;
        bad |= (fabsf(Ads[s] - tgt) > 1e-5f * fabsf(tgt) + 1e-30f) ? 1 : 0;
    }
    __syncthreads();
    if (bad) atomicOr(&sflag, 1);
    __syncthreads();
    const int structured = (sflag == 0);

    const size_t rowbase = (size_t)b * LL + c * CH;
    float dsum = 0.f;

    if (structured) {
        f32x2 h2[8] = {};
        for (int t0 = 0; t0 < CH; t0 += TT) {
            #pragma unroll
            for (int pp = 0; pp < 2; pp++) {
                int r0 = (pp * 4 + w) * 2;
                size_t grow = rowbase + t0 + r0 + lrow;
                gld_lds16(dty + grow * DI + d0 + lcol, &sdt[r0][0]);
                gld_lds16(xc  + grow * DI + d0 + lcol, &su[r0][0]);
            }
            if (w < 2)
                gld_lds16(xdbl + (rowbase + t0 + w * 8 + brow) * 96 + DTR + bcol,
                          &sBC[w * 8][0]);
            __syncthreads();
            #pragma unroll
            for (int t = 0; t < TT; t++) {
                float dtv = b2f(sdt[t][tid]);
                float uv  = b2f(su[t][tid]);
                float tmp = dtv * uv;
                dsum += dtv;
                float4 B0 = ((const float4*)&sBC[t][0])[0];
                float4 B1 = ((const float4*)&sBC[t][0])[1];
                float4 B2 = ((const float4*)&sBC[t][0])[2];
                float4 B3 = ((const float4*)&sBC[t][0])[3];
                f32x2 bv2[8] = {{B0.x,B0.y},{B0.z,B0.w},{B1.x,B1.y},{B1.z,B1.w},
                                {B2.x,B2.y},{B2.z,B2.w},{B3.x,B3.y},{B3.z,B3.w}};
                f32x2 dA2[8];
                dA2_tree(__expf(dtv * A0), dA2);
                f32x2 tmp2 = {tmp, tmp};
                #pragma unroll
                for (int i = 0; i < 8; i++)
                    h2[i] = dA2[i] * h2[i] + tmp2 * bv2[i];
            }
            __syncthreads();
        }
        size_t o = ((size_t)(b * NCC + c) * DI + d) * DS;
        Pd[(size_t)(b * NCC + c) * DI + d] = dsum;
        #pragma unroll
        for (int q = 0; q < 4; q++)
            *(float4*)&S[o + q*4] = make_float4(h2[q*2].x, h2[q*2].y,
                                                h2[q*2+1].x, h2[q*2+1].y);
    } else {
        float h[16];
        #pragma unroll
        for (int s = 0; s < 16; s++) h[s] = 0.f;
        for (int t0 = 0; t0 < CH; t0 += TT) {
            #pragma unroll
            for (int pp = 0; pp < 2; pp++) {
                int r0 = (pp * 4 + w) * 2;
                size_t grow = rowbase + t0 + r0 + lrow;
                gld_lds16(dty + grow * DI + d0 + lcol, &sdt[r0][0]);
                gld_lds16(xc  + grow * DI + d0 + lcol, &su[r0][0]);
            }
            if (w < 2)
                gld_lds16(xdbl + (rowbase + t0 + w * 8 + brow) * 96 + DTR + bcol,
                          &sBC[w * 8][0]);
            __syncthreads();
            for (int t = 0; t < TT; t++) {
                float dtv = b2f(sdt[t][tid]);
                float uv  = b2f(su[t][tid]);
                float tmp = dtv * uv;
                dsum += dtv;
                const float4* bc = (const float4*)&sBC[t][0];
                float4 B0 = bc[0], B1 = bc[1], B2 = bc[2], B3 = bc[3];
                float Bv[16] = {B0.x,B0.y,B0.z,B0.w, B1.x,B1.y,B1.z,B1.w,
                                B2.x,B2.y,B2.z,B2.w, B3.x,B3.y,B3.z,B3.w};
                #pragma unroll
                for (int s = 0; s < 16; s++) {
                    float dA = __expf(dtv * Ads[s]);
                    h[s] = dA * h[s] + tmp * Bv[s];
                }
            }
            __syncthreads();
        }
        size_t o = ((size_t)(b * NCC + c) * DI + d) * DS;
        Pd[(size_t)(b * NCC + c) * DI + d] = dsum;
        #pragma unroll
        for (int q = 0; q < 4; q++)
            *(float4*)&S[o + q*4] = make_float4(h[q*4], h[q*4+1], h[q*4+2], h[q*4+3]);
    }
}

// combine: P[s] = exp(Ads[s]*dsum) recomputed from dsum scalar (exact).
template<int NCC>
__global__ __launch_bounds__(256) void scan_combine(
    const float* __restrict__ A_log, const float* __restrict__ Pd,
    float* __restrict__ S)
{
    int g = blockIdx.x * 256 + threadIdx.x;   // B*DI*DS threads
    int b = g >> 15;                          // DI*DS = 32768
    int rem = g & 32767;
    int d = rem >> 4;
    float Ads = -__expf(A_log[rem]);          // A_log layout [DI][DS]
    float h = 0.f;
    #pragma unroll
    for (int c = 0; c < NCC; c++) {
        size_t os = ((size_t)(b * NCC + c) << 15) + rem;
        float p = __expf(Ads * Pd[(size_t)(b * NCC + c) * DI + d]);
        float sv = S[os];
        S[os] = h;                            // h_in for chunk c
        h = p * h + sv;
    }
}

template<int NCC>
__global__ __launch_bounds__(256) void scan_part2(
    const float* __restrict__ xdbl, bf16* __restrict__ dty,
    const bf16* __restrict__ xc, const bf16* __restrict__ xz,
    const float* __restrict__ A_log, const float* __restrict__ Dp,
    const float* __restrict__ Hin)
{
    __shared__ bf16 sdt[TT][TCH];
    __shared__ bf16 su[TT][TCH];
    __shared__ bf16 sz[TT][TCH];
    __shared__ alignas(16) float sBC[TT][32];
    __shared__ int sflag;
    const int CH = LL / NCC;
    int bid = blockIdx.x;
    int cg = bid & 7;
    int c  = (bid >> 3) & (NCC - 1);
    int b  = (bid >> 3) / NCC;
    int d0 = cg * TCH;
    int tid = threadIdx.x;
    int w = tid >> 6, l = tid & 63;
    int lrow = l >> 5, lcol = (l & 31) * 8;
    int brow = l >> 3, bcol = (l & 7) * 4;
    int d = d0 + tid;

    if (tid == 0) sflag = 0;
    float Ads[16];
    #pragma unroll
    for (int q = 0; q < 4; q++) {
        float4 a4 = *(const float4*)&A_log[(size_t)d * DS + q * 4];
        Ads[q*4+0] = -__expf(a4.x); Ads[q*4+1] = -__expf(a4.y);
        Ads[q*4+2] = -__expf(a4.z); Ads[q*4+3] = -__expf(a4.w);
    }
    const float A0 = Ads[0];
    int bad = 0;
    #pragma unroll
    for (int s = 1; s < 16; s++) {
        float tgt = (float)(s + 1) * A0;
        bad |= (fabsf(Ads[s] - tgt) > 1e-5f * fabsf(tgt) + 1e-30f) ? 1 : 0;
    }
    __syncthreads();
    if (bad) atomicOr(&sflag, 1);
    __syncthreads();
    const int structured = (sflag == 0);

    float dpd = Dp[d];
    size_t ho = ((size_t)(b * NCC + c) * DI + d) * DS;
    const size_t rowbase = (size_t)b * LL + c * CH;

    if (structured) {
        f32x2 h2[8];
        #pragma unroll
        for (int q = 0; q < 4; q++) {
            float4 hv = *(const float4*)&Hin[ho + q*4];
            h2[q*2]   = (f32x2){hv.x, hv.y};
            h2[q*2+1] = (f32x2){hv.z, hv.w};
        }
        for (int t0 = 0; t0 < CH; t0 += TT) {
            #pragma unroll
            for (int pp = 0; pp < 2; pp++) {
                int r0 = (pp * 4 + w) * 2;
                size_t grow = rowbase + t0 + r0 + lrow;
                gld_lds16(dty + grow * DI + d0 + lcol, &sdt[r0][0]);
                gld_lds16(xc  + grow * DI + d0 + lcol, &su[r0][0]);
                gld_lds16(xz  + grow * (2 * DI) + DI + d0 + lcol, &sz[r0][0]);
            }
            if (w < 2)
                gld_lds16(xdbl + (rowbase + t0 + w * 8 + brow) * 96 + DTR + bcol,
                          &sBC[w * 8][0]);
            __syncthreads();
            #pragma unroll
            for (int t = 0; t < TT; t++) {
                float dtv = b2f(sdt[t][tid]);
                float uv  = b2f(su[t][tid]);
                float tmp = dtv * uv;
                const float4* bc = (const float4*)&sBC[t][0];
                float4 B0 = bc[0], B1 = bc[1], B2 = bc[2], B3 = bc[3];
                float4 C0 = bc[4], C1 = bc[5], C2 = bc[6], C3 = bc[7];
                f32x2 bv2[8] = {{B0.x,B0.y},{B0.z,B0.w},{B1.x,B1.y},{B1.z,B1.w},
                                {B2.x,B2.y},{B2.z,B2.w},{B3.x,B3.y},{B3.z,B3.w}};
                f32x2 cv2[8] = {{C0.x,C0.y},{C0.z,C0.w},{C1.x,C1.y},{C1.z,C1.w},
                                {C2.x,C2.y},{C2.z,C2.w},{C3.x,C3.y},{C3.z,C3.w}};
                f32x2 dA2[8];
                dA2_tree(__expf(dtv * A0), dA2);
                f32x2 tmp2 = {tmp, tmp};
                f32x2 y2 = {0.f, 0.f};
                #pragma unroll
                for (int i = 0; i < 8; i++) {
                    h2[i] = dA2[i] * h2[i] + tmp2 * bv2[i];
                    y2 = y2 + h2[i] * cv2[i];
                }
                float y = y2.x + y2.y;
                float zv = b2f(sz[t][tid]);
                float yo = (y + uv * dpd) * (zv / (1.f + __expf(-zv)));
                dty[(rowbase + t0 + t) * DI + d] = f2b(yo);
            }
            __syncthreads();
        }
    } else {
        float h[16];
        #pragma unroll
        for (int q = 0; q < 4; q++) {
            float4 hv = *(const float4*)&Hin[ho + q*4];
            h[q*4] = hv.x; h[q*4+1] = hv.y; h[q*4+2] = hv.z; h[q*4+3] = hv.w;
        }
        for (int t0 = 0; t0 < CH; t0 += TT) {
            #pragma unroll
            for (int pp = 0; pp < 2; pp++) {
                int r0 = (pp * 4 + w) * 2;
                size_t grow = rowbase + t0 + r0 + lrow;
                gld_lds16(dty + grow * DI + d0 + lcol, &sdt[r0][0]);
                gld_lds16(xc  + grow * DI + d0 + lcol, &su[r0][0]);
                gld_lds16(xz  + grow * (2 * DI) + DI + d0 + lcol, &sz[r0][0]);
            }
            if (w < 2)
                gld_lds16(xdbl + (rowbase + t0 + w * 8 + brow) * 96 + DTR + bcol,
                          &sBC[w * 8][0]);
            __syncthreads();
            for (int t = 0; t < TT; t++) {
                float dtv = b2f(sdt[t][tid]);
                float uv  = b2f(su[t][tid]);
                float tmp = dtv * uv;
                const float4* bc = (const float4*)&sBC[t][0];
                float4 B0 = bc[0], B1 = bc[1], B2 = bc[2], B3 = bc[3];
                float4 C0 = bc[4], C1 = bc[5], C2 = bc[6], C3 = bc[7];
                float Bv[16] = {B0.x,B0.y,B0.z,B0.w, B1.x,B1.y,B1.z,B1.w,
                                B2.x,B2.y,B2.z,B2.w, B3.x,B3.y,B3.z,B3.w};
                float Cv[16] = {C0.x,C0.y,C0.z,C0.w, C1.x,C1.y,C1.z,C1.w,
                                C2.x,C2.y,C2.z,C2.w, C3.x,C3.y,C3.z,C3.w};
                float y0 = 0.f, y1 = 0.f;
                #pragma unroll
                for (int s = 0; s < 16; s++) {
                    float dA = __expf(dtv * Ads[s]);
                    h[s] = dA * h[s] + tmp * Bv[s];
                    if (s & 1) y1 = fmaf(h[s], Cv[s], y1);
                    else       y0 = fmaf(h[s], Cv[s], y0);
                }
                float y = y0 + y1;
                float zv = b2f(sz[t][tid]);
                float yo = (y + uv * dpd) * (zv / (1.f + __expf(-zv)));
                dty[(rowbase + t0 + t) * DI + d] = f2b(yo);
            }
            __syncthreads();
        }
    }
}

// ---------------- Monolithic scan (fallback when ws is small) ----------------
__global__ __launch_bounds__(256) void scan_mono(
    const float* __restrict__ xdbl, bf16* __restrict__ dty,
    const bf16* __restrict__ xc, const bf16* __restrict__ xz,
    const float* __restrict__ A_log, const float* __restrict__ Dp)
{
    const int TC = 64;
    int b = blockIdx.x >> 7;
    int dblk = blockIdx.x & 127;
    int d0 = dblk * 16;
    int tid = threadIdx.x;
    int s = tid & 15;
    int dg = tid >> 4;
    int d = d0 + dg;
    float Ads = -__expf(A_log[(size_t)d * DS + s]);
    float h = 0.f;
    __shared__ float sdt[TC][16], su[TC][16], sB[TC][16], sC[TC][16], sy[TC][16];
    const size_t rowbase = (size_t)b * LL;
    int wi = tid >> 2;
    int wj = (tid & 3) * 4;
    float4 dpv = *(const float4*)(Dp + d0 + wj);
    for (int t0 = 0; t0 < LL; t0 += TC) {
        {
            size_t g = (rowbase + t0 + wi) * (size_t)DI + d0 + wj;
            *(float4*)&sdt[wi][wj] = ld4(dty + g);
            *(float4*)&su[wi][wj]  = ld4(xc + g);
        }
        #pragma unroll
        for (int r = 0; r < 4; r++) {
            int i = (tid >> 4) + r * 16;
            size_t g = (rowbase + t0 + i) * 96;
            sB[i][s] = xdbl[g + DTR + s];
            sC[i][s] = xdbl[g + DTR + DS + s];
        }
        __syncthreads();
        for (int i = 0; i < TC; i++) {
            float dtv = sdt[i][dg];
            float dA = __expf(dtv * Ads);
            h = dA * h + dtv * su[i][dg] * sB[i][s];
            float yp = h * sC[i][s];
            yp += __shfl_xor(yp, 1);
            yp += __shfl_xor(yp, 2);
            yp += __shfl_xor(yp, 4);
            yp += __shfl_xor(yp, 8);
            if (s == 0) sy[i][dg] = yp;
        }
        __syncthreads();
        {
            size_t g  = (rowbase + t0 + wi) * (size_t)DI + d0 + wj;
            size_t gz = (rowbase + t0 + wi) * (size_t)(2 * DI) + DI + d0 + wj;
            float4 zv = ld4(xz + gz);
            float4 yv = *(const float4*)&sy[wi][wj];
            float4 uv = *(const float4*)&su[wi][wj];
            ushort4 o;
            o.x = f2b((yv.x + uv.x * dpv.x) * (zv.x / (1.f + __expf(-zv.x))));
            o.y = f2b((yv.y + uv.y * dpv.y) * (zv.y / (1.f + __expf(-zv.y))));
            o.z = f2b((yv.z + uv.z * dpv.z) * (zv.z / (1.f + __expf(-zv.z))));
            o.w = f2b((yv.w + uv.w * dpv.w) * (zv.w / (1.f + __expf(-zv.w))));
            *(ushort4*)(dty + g) = o;
        }
        __syncthreads();
    }
}

// ---------------- slow conv (fallback path: f32 weights, 4 ch/thread) --------
__global__ __launch_bounds__(256) void conv_silu_slow(
    const bf16* __restrict__ xz, const float* __restrict__ cw,
    const float* __restrict__ cb, bf16* __restrict__ xc)
{
    int idx = blockIdx.x * 256 + threadIdx.x;
    int d4 = idx & (DI / 4 - 1);
    int bl = idx >> 9;
    int l = bl & (LL - 1);
    int d0 = d4 * 4;
    float4 bias = *(const float4*)(cb + d0);
    float acc[4] = {bias.x, bias.y, bias.z, bias.w};
    #pragma unroll
    for (int k = 0; k < 4; k++) {
        if (l - 3 + k < 0) continue;
        float4 xv = ld4(xz + (size_t)(bl - 3 + k) * (2 * DI) + d0);
        acc[0] = fmaf(xv.x, cw[(d0 + 0) * 4 + k], acc[0]);
        acc[1] = fmaf(xv.y, cw[(d0 + 1) * 4 + k], acc[1]);
        acc[2] = fmaf(xv.z, cw[(d0 + 2) * 4 + k], acc[2]);
        acc[3] = fmaf(xv.w, cw[(d0 + 3) * 4 + k], acc[3]);
    }
    ushort4 o;
    o.x = f2b(acc[0] / (1.f + __expf(-acc[0])));
    o.y = f2b(acc[1] / (1.f + __expf(-acc[1])));
    o.z = f2b(acc[2] / (1.f + __expf(-acc[2])));
    o.w = f2b(acc[3] / (1.f + __expf(-acc[3])));
    *(ushort4*)(xc + (size_t)bl * DI + d0) = o;
}

// ---------------------------------------------------------------------------
extern "C" void kernel_launch(void* const* d_in, const int* in_sizes, int n_in,
                              void* d_out, int out_size, void* d_ws, size_t ws_size,
                              hipStream_t stream)
{
    const float* x      = (const float*)d_in[0];
    const float* ln_w   = (const float*)d_in[1];
    const float* ln_b   = (const float*)d_in[2];
    const float* W_in   = (const float*)d_in[3];
    const float* conv_w = (const float*)d_in[4];
    const float* conv_b = (const float*)d_in[5];
    const float* W_x    = (const float*)d_in[6];
    const float* W_dt   = (const float*)d_in[7];
    const float* b_dt   = (const float*)d_in[8];
    const float* A_log  = (const float*)d_in[9];
    const float* Dp     = (const float*)d_in[10];
    const float* W_out  = (const float*)d_in[11];
    float* out = (float*)d_out;

    const size_t R = (size_t)BB * LL;   // 8192 rows

    // ws: xz bf16 | dty bf16 | xdbl f32 | Pd,S f32 (NCC-sized) | W_x_b | W_dt_b
    //     | dtr bf16 | cwt bf16 | [W_out_b2 bf16 if room]
    bf16*  xz    = (bf16*)d_ws;                    // R * 2*DI
    bf16*  dty   = xz + R * 2 * DI;                // R * DI
    float* xdbl  = (float*)(dty + R * DI);         // R * 96
    float* Pbuf  = xdbl + R * 96;                  // dsum: BB*NCC*DI floats

    const size_t headB = (size_t)((char*)Pbuf - (char*)d_ws);
    const size_t tailB = (size_t)(128 * DI + DI * DTR + R * DTR + 4 * DI) * 2 + 64;
    const size_t pU = (size_t)BB * DI * 4;           // dsum bytes per chunk
    const size_t sU = (size_t)BB * DI * DS * 4;      // S bytes per chunk
    const int ncc = (ws_size >= headB + 32 * (pU + sU) + tailB) ? 32 : 16;

    float* Sbuf   = (float*)((char*)Pbuf + (size_t)ncc * pU);
    bf16*  W_x_b  = (bf16*)((char*)Sbuf + (size_t)ncc * sU); // 128*DI (96 used)
    bf16*  W_dt_b = W_x_b + 128 * DI;              // DI * DTR
    bf16*  dtr    = W_dt_b + DI * DTR;             // R * DTR
    bf16*  cwt    = dtr + R * DTR;                 // 4 * DI
    bf16*  W_out_b2 = cwt + 4 * DI;                // DM * DI (optional)
    const size_t ws_need = (size_t)((char*)(cwt + 4 * DI) - (char*)d_ws);
    const bool fast = ws_size >= ws_need;
    const size_t ws_need_w = (size_t)((char*)(W_out_b2 + (size_t)DM * DI) - (char*)d_ws);
    const int dowout = (fast && ws_size >= ws_need_w) ? 1 : 0;

    bf16*  W_in_b  = dty;   // dead before dt-gemm writes dty
    bf16*  W_out_b = xz;    // late-convert fallback (z dead after scan)

    bf16* xn = (bf16*)d_out;
    bf16* xc = (bf16*)d_out;

    // 0+1. fused prologue: LayerNorm + all weight converts (1 launch)
    {
        int nb = BB * LL + 4096;                    // LN + W_in
        if (fast) nb += 192 + 128 + 8 + (dowout ? 2048 : 0);
        prep_kernel<<<nb, 256, 0, stream>>>(
            x, ln_w, ln_b, xn, W_in, W_in_b, W_x, W_x_b, W_dt, W_dt_b,
            conv_w, cwt, W_out, W_out_b2, fast ? 1 : 0, dowout);
    }

    // 2. in_proj (8-phase 256^2 MFMA, WAR-interleave): xz = xn @ W_in^T
    for (int half = 0; half < 2; half++) {
        gemm_8p<0, bf16><<<dim3(16 * 16), 512, 0, stream>>>(
            xn + (size_t)half * 4096 * DM, DM, W_in_b, DM,
            xz + (size_t)half * 4096 * (2 * DI), 2 * DI, DM, nullptr, 16);
    }

    if (fast) {
        // 3. conv + SiLU -> xc (8 ch/thread, tap-major bf16 weights)
        conv_silu_kernel<<<(int)(R * DI / 8 / 256), 256, 0, stream>>>(
            xz, cwt, conv_b, xc);
        // 4a. x_proj MFMA -> xdbl f32 + dtr bf16
        xproj_mfma<<<(int)(R / 32), 256, 0, stream>>>(xc, W_x_b, xdbl, dtr);
        // 4b. dt = softplus(dtr @ W_dt^T + b_dt) -> dty bf16 (MFMA, K=64)
        gemm_mfma<1, bf16><<<dim3(DI / 128, R / 128), 256, 0, stream>>>(
            dtr, DTR, W_dt_b, DTR, dty, DI, DTR, b_dt);
        // 5. chunked scan (NCC chunks, TT=16 staged tiles)
        if (ncc == 32) {
            scan_part1<32><<<BB * 32 * (DI / TCH), 256, 0, stream>>>(
                xdbl, dty, xc, A_log, Pbuf, Sbuf);
            scan_combine<32><<<BB * DI * DS / 256, 256, 0, stream>>>(
                A_log, Pbuf, Sbuf);
            scan_part2<32><<<BB * 32 * (DI / TCH), 256, 0, stream>>>(
                xdbl, dty, xc, xz, A_log, Dp, Sbuf);
        } else {
            scan_part1<16><<<BB * 16 * (DI / TCH), 256, 0, stream>>>(
                xdbl, dty, xc, A_log, Pbuf, Sbuf);
            scan_combine<16><<<BB * DI * DS / 256, 256, 0, stream>>>(
                A_log, Pbuf, Sbuf);
            scan_part2<16><<<BB * 16 * (DI / TCH), 256, 0, stream>>>(
                xdbl, dty, xc, xz, A_log, Dp, Sbuf);
        }
    } else {
        // fallback: slow conv + f32 small GEMMs + monolithic scan
        conv_silu_slow<<<(int)(R * DI / 4 / 256), 256, 0, stream>>>(
            xz, conv_w, conv_b, xc);
        gemm_nt<0><<<dim3(2, R / 64), 256, 0, stream>>>(
            xc, DI, W_x, DI, xdbl, 96, (int)R, 96, DI, nullptr);
        gemm_nt<1><<<dim3(DI / 64, R / 64), 256, 0, stream>>>(
            xdbl, 96, W_dt, DTR, dty, DI, (int)R, DI, DTR, b_dt);
        scan_mono<<<BB * (DI / 16), 256, 0, stream>>>(
            xdbl, dty, xc, xz, A_log, Dp);
    }

    // 5b. late W_out convert only if no dedicated buffer (z dead after scan)
    const bf16* W_out_use = dowout ? (const bf16*)W_out_b2 : (const bf16*)W_out_b;
    if (!dowout)
        f2b_kernel<<<(DM * DI / 4) / 256, 256, 0, stream>>>(W_out, W_out_b, DM * DI / 4);

    // 6. out_proj (8-phase 256x128 MFMA, full-GPU grid, WAR-interleave)
    gemm_8p_n128<2, float><<<dim3((int)(R / 256) * (DM / 128)), 512, 0, stream>>>(
        dty, DI, W_out_use, DI, out, DM, DI, x, DM / 128);
}